// Round 10
// baseline (209.830 us; speedup 1.0000x reference)
//
#include <hip/hip_runtime.h>
#include <math.h>

#define BN_EPS 1e-5f
#define ROWS 32

typedef __attribute__((ext_vector_type(8))) short short8;
typedef __attribute__((ext_vector_type(4))) float float4v;

__device__ __forceinline__ unsigned short f2bf(float f) {
    union { float f; unsigned int u; } v; v.f = f;
    unsigned int r = v.u + 0x7FFF + ((v.u >> 16) & 1);   // RNE
    return (unsigned short)(r >> 16);
}
__device__ __forceinline__ float softplus_f(float v) {
    float e = __expf(-fabsf(v));
    float r = __logf(1.f + e);
    return v > 0.f ? v + r : r;
}
__device__ __forceinline__ float swish_f(float a) {
    return a / (1.f + __expf(-a));
}

__device__ __forceinline__ float max16(const float* p) {
    float a = fmaxf(p[0], p[1]),  b = fmaxf(p[2], p[3]);
    float c = fmaxf(p[4], p[5]),  d = fmaxf(p[6], p[7]);
    float e = fmaxf(p[8], p[9]),  f = fmaxf(p[10], p[11]);
    float g = fmaxf(p[12], p[13]), h = fmaxf(p[14], p[15]);
    a = fmaxf(a, b); c = fmaxf(c, d); e = fmaxf(e, f); g = fmaxf(g, h);
    return fmaxf(fmaxf(a, c), fmaxf(e, g));
}

// ---- prep: WIDE elementwise (read-coalesced, write-scatter merged in L2) ----
#define PREP_WIDE_THREADS (1536 * 128 + 128 * 128)   // 212992 -> 832 blocks
__global__ void prep_weights(const float* __restrict__ W0, const float* __restrict__ W1,
                             const float* __restrict__ W2, const float* __restrict__ b0,
                             const float* __restrict__ b2,
                             const float* __restrict__ bn_scale, const float* __restrict__ bn_bias,
                             const float* __restrict__ bn_mean, const float* __restrict__ bn_var,
                             unsigned short* __restrict__ Wt0, unsigned short* __restrict__ Wt1,
                             unsigned short* __restrict__ Wt2, float* __restrict__ b0p,
                             float* __restrict__ b2p) {
    const int bid = blockIdx.x, tid = threadIdx.x;
    if (bid < 832) {
        int i = bid * 256 + tid;
        if (i < 1536 * 128) {
            int k = i / 1536, colp = i - k * 1536;
            int dd = colp / 48, j = colp - dd * 48;
            float v = (j < 47) ? W2[k * 1504 + dd * 47 + j] : 0.f;
            Wt2[(size_t)colp * 128 + k] = f2bf(v);
        } else {
            int i2 = i - 1536 * 128;
            int k = i2 >> 7, n = i2 & 127;
            Wt1[n * 128 + k] = f2bf(W1[k * 128 + n]);
        }
        return;
    }
    if (bid == 832) {
        __shared__ float lds[48 * 129 + 96];
        float* a   = lds + 48 * 129;
        float* bsh = a + 48;
        if (tid < 48) {
            float av = bn_scale[tid] * rsqrtf(bn_var[tid] + BN_EPS);
            a[tid] = av;
            bsh[tid] = bn_bias[tid] - bn_mean[tid] * av;
        }
        for (int idx = tid; idx < 48 * 128; idx += 256) {
            int k = idx >> 7, n = idx & 127;
            lds[k * 129 + n] = W0[k * 128 + n];
        }
        __syncthreads();
        #pragma unroll 4
        for (int it = 0; it < 32; ++it) {
            int n = (tid >> 6) + it * 4;
            int k = tid & 63;
            float v = (k < 48) ? lds[k * 129 + n] * a[k] : 0.f;
            Wt0[n * 64 + k] = f2bf(v);
        }
        if (tid < 128) {
            float s = b0[tid];
            #pragma unroll
            for (int k = 0; k < 48; ++k) s += bsh[k] * lds[k * 129 + tid];
            b0p[tid] = s;
        }
        return;
    }
    for (int e = tid; e < 32 * 48; e += 256) {
        int dd = e / 48, j = e - dd * 48;
        b2p[e] = (j < 47) ? b2[dd * 47 + j] : 0.f;
    }
}

// Round-9 lesson: time invariant under VALU deletion (VALUBusy 47->42, dur 86us
// unchanged) and under scheduling changes -> the binding constraint is stall
// structure at 3-blocks-resident / 4-blocks-work per CU with 4-wave lockstep
// barriers. This version halves the block: ROWS=32, 128 threads (2 waves),
// LDS 19456B -> 8 blocks/CU resident, grid 2048 = exactly 8 blocks/CU of work
// (no resident/work mismatch), 2-wave barriers, 8 independent barrier groups
// fill each other's stalls. Phase 4 processes TWO d's per pass (lanes 0-31: d,
// lanes 32-63: d+8; pw rows 32-63 carry the second d) so all 64 lanes stay
// productive. Same conflict-free stride-20 pw; spline = round-9 descent math.
__launch_bounds__(128, 4)
__global__ void nsc_mfma(const float* __restrict__ x, const float* __restrict__ c,
                         const unsigned short* __restrict__ Wt0, const float* __restrict__ b0p,
                         const unsigned short* __restrict__ Wt1, const float* __restrict__ b1,
                         const unsigned short* __restrict__ Wt2, const float* __restrict__ b2p,
                         float* __restrict__ out, int N) {
    // region A [0,8704):        h0 [32][72] bf16 -> h2 [32][136] bf16 (live through GEMM2)
    // region B [8704,19456):    h1 [32][136] bf16 (8704) -> pw 2x[64][20] f32 (10240) + ldp [4][32] f32 (512)
    __shared__ __align__(16) char smem[19456];
    unsigned short* h0 = (unsigned short*)smem;            // stride 72
    unsigned short* h2 = (unsigned short*)smem;            // stride 136
    unsigned short* h1 = (unsigned short*)(smem + 8704);   // stride 136
    float*          ldp = (float*)(smem + 8704 + 10240);   // [4][32]

    const int tid  = threadIdx.x;
    const int lane = tid & 63;
    const int l    = lane & 15;
    const int q    = lane >> 4;
    const int wu   = __builtin_amdgcn_readfirstlane(tid >> 6);   // 0..1
    const int r0   = blockIdx.x * ROWS;
    float* pw = (float*)(smem + 8704) + wu * (64 * 20);    // per-wave staging, stride 20

    // ---- phase 1: raw inputs -> h0 bf16 (BN folded into W0); xc passthrough ----
    for (int idx = tid; idx < 32 * 64; idx += 128) {
        int r = idx >> 6, j = idx & 63;
        float h = 0.f;
        if (j < 48) {
            int row = r0 + r;
            h = (j < 32) ? x[(size_t)row * 64 + 32 + j] : c[(size_t)row * 16 + (j - 32)];
        }
        h0[r * 72 + j] = f2bf(h);
    }
    for (int idx = tid; idx < 32 * 8; idx += 128) {
        int r = idx >> 3, ch = idx & 7;
        float4v v = *(const float4v*)(x + (size_t)(r0 + r) * 64 + 32 + ch * 4);
        *(float4v*)(out + (size_t)(r0 + r) * 64 + 32 + ch * 4) = v;
    }
    __syncthreads();

    // ---- phase 2: GEMM0  h1 = swish(h0 @ W0' + b0'), M=32 N=128 K=64(padded) ----
    {
        float4v acc[4][2];
        float4v z = {0.f, 0.f, 0.f, 0.f};
        #pragma unroll
        for (int nt = 0; nt < 4; ++nt)
            #pragma unroll
            for (int mt = 0; mt < 2; ++mt) acc[nt][mt] = z;
        #pragma unroll
        for (int ks = 0; ks < 2; ++ks) {
            short8 a[2];
            #pragma unroll
            for (int mt = 0; mt < 2; ++mt)
                a[mt] = *(const short8*)(h0 + (mt * 16 + l) * 72 + ks * 32 + (q << 3));
            #pragma unroll
            for (int nt = 0; nt < 4; ++nt) {
                int n0 = (wu * 4 + nt) * 16;
                short8 b = *(const short8*)(Wt0 + (n0 + l) * 64 + ks * 32 + (q << 3));
                #pragma unroll
                for (int mt = 0; mt < 2; ++mt)
                    acc[nt][mt] = __builtin_amdgcn_mfma_f32_16x16x32_bf16(a[mt], b, acc[nt][mt], 0, 0, 0);
            }
        }
        #pragma unroll
        for (int nt = 0; nt < 4; ++nt) {
            int n0 = (wu * 4 + nt) * 16;
            float bb = b0p[n0 + l];
            #pragma unroll
            for (int mt = 0; mt < 2; ++mt)
                #pragma unroll
                for (int r = 0; r < 4; ++r)
                    h1[(mt * 16 + q * 4 + r) * 136 + n0 + l] = f2bf(swish_f(acc[nt][mt][r] + bb));
        }
    }
    __syncthreads();

    // ---- phase 3: GEMM1  h2 = swish(h1 @ W1 + b1), M=32 N=128 K=128 ----
    {
        float4v acc[4][2];
        float4v z = {0.f, 0.f, 0.f, 0.f};
        #pragma unroll
        for (int nt = 0; nt < 4; ++nt)
            #pragma unroll
            for (int mt = 0; mt < 2; ++mt) acc[nt][mt] = z;
        #pragma unroll
        for (int ks = 0; ks < 4; ++ks) {
            short8 a[2];
            #pragma unroll
            for (int mt = 0; mt < 2; ++mt)
                a[mt] = *(const short8*)(h1 + (mt * 16 + l) * 136 + ks * 32 + (q << 3));
            #pragma unroll
            for (int nt = 0; nt < 4; ++nt) {
                int n0 = (wu * 4 + nt) * 16;
                short8 b = *(const short8*)(Wt1 + (n0 + l) * 128 + ks * 32 + (q << 3));
                #pragma unroll
                for (int mt = 0; mt < 2; ++mt)
                    acc[nt][mt] = __builtin_amdgcn_mfma_f32_16x16x32_bf16(a[mt], b, acc[nt][mt], 0, 0, 0);
            }
        }
        #pragma unroll
        for (int nt = 0; nt < 4; ++nt) {
            int n0 = (wu * 4 + nt) * 16;
            float bb = b1[n0 + l];
            #pragma unroll
            for (int mt = 0; mt < 2; ++mt)
                #pragma unroll
                for (int r = 0; r < 4; ++r)
                    h2[(mt * 16 + q * 4 + r) * 136 + n0 + l] = f2bf(swish_f(acc[nt][mt][r] + bb));
        }
    }
    __syncthreads();   // h1 dead -> pw reuses region B; h2 live in region A

    // ---- phase 4: GEMM2 (swapped: p^T tiles, TWO d's per pass) + spline ----
    const int half = lane >> 5;          // 0 -> d0 block, 1 -> d1 = d0+8 block
    const int row  = lane & 31;
    float ld_local = 0.f;
    float yreg[8];
    for (int pass = 0; pass < 8; ++pass) {
        const int d0 = wu * 16 + pass;
        const int d1 = d0 + 8;
        const int dme = half ? d1 : d0;
        float t = x[(size_t)(r0 + row) * 64 + dme];   // issued early
        float4v bj00 = *(const float4v*)(b2p + d0 * 48 +      (q << 2));
        float4v bj01 = *(const float4v*)(b2p + d0 * 48 + 16 + (q << 2));
        float4v bj02 = *(const float4v*)(b2p + d0 * 48 + 32 + (q << 2));
        float4v bj10 = *(const float4v*)(b2p + d1 * 48 +      (q << 2));
        float4v bj11 = *(const float4v*)(b2p + d1 * 48 + 16 + (q << 2));
        float4v bj12 = *(const float4v*)(b2p + d1 * 48 + 32 + (q << 2));
        bool inb = (t >= 0.f) && (t <= 1.f);
        float tc = fminf(fmaxf(t, 0.f), 1.f);

        float4v acc0[3][2], acc1[3][2];
        float4v z = {0.f, 0.f, 0.f, 0.f};
        #pragma unroll
        for (int jt = 0; jt < 3; ++jt)
            #pragma unroll
            for (int smt = 0; smt < 2; ++smt) { acc0[jt][smt] = z; acc1[jt][smt] = z; }
        __builtin_amdgcn_s_setprio(1);
        #pragma unroll
        for (int ks = 0; ks < 4; ++ks) {
            short8 bf[2];
            #pragma unroll
            for (int smt = 0; smt < 2; ++smt)
                bf[smt] = *(const short8*)(h2 + (smt * 16 + l) * 136 + ks * 32 + (q << 3));
            #pragma unroll
            for (int jt = 0; jt < 3; ++jt) {
                short8 a0 = *(const short8*)(Wt2 + (size_t)(d0 * 48 + jt * 16 + l) * 128 + ks * 32 + (q << 3));
                short8 a1 = *(const short8*)(Wt2 + (size_t)(d1 * 48 + jt * 16 + l) * 128 + ks * 32 + (q << 3));
                #pragma unroll
                for (int smt = 0; smt < 2; ++smt) {
                    acc0[jt][smt] = __builtin_amdgcn_mfma_f32_16x16x32_bf16(a0, bf[smt], acc0[jt][smt], 0, 0, 0);
                    acc1[jt][smt] = __builtin_amdgcn_mfma_f32_16x16x32_bf16(a1, bf[smt], acc1[jt][smt], 0, 0, 0);
                }
            }
        }
        __builtin_amdgcn_s_setprio(0);

        float prW[16], prH[16];
        // ---- DS burst (per-wave in-order queue): W-writes (d0 rows 0-31,
        //      d1 rows 32-63), W-read, H-writes, H-read, D-writes in flight;
        //      W-compute overlaps H/D round-trips.
        #pragma unroll
        for (int smt = 0; smt < 2; ++smt) {
            *(float4v*)(pw + (smt * 16 + l) * 20 + (q << 2))        = acc0[0][smt] + bj00;
            *(float4v*)(pw + (32 + smt * 16 + l) * 20 + (q << 2))   = acc1[0][smt] + bj10;
        }
        #pragma unroll
        for (int c2 = 0; c2 < 4; ++c2)
            *(float4v*)(prW + c2 * 4) = *(const float4v*)(pw + lane * 20 + c2 * 4);
        #pragma unroll
        for (int smt = 0; smt < 2; ++smt) {
            *(float4v*)(pw + (smt * 16 + l) * 20 + (q << 2))        = acc0[1][smt] + bj01;
            *(float4v*)(pw + (32 + smt * 16 + l) * 20 + (q << 2))   = acc1[1][smt] + bj11;
        }
        #pragma unroll
        for (int c2 = 0; c2 < 4; ++c2)
            *(float4v*)(prH + c2 * 4) = *(const float4v*)(pw + lane * 20 + c2 * 4);
        #pragma unroll
        for (int smt = 0; smt < 2; ++smt) {
            *(float4v*)(pw + (smt * 16 + l) * 20 + (q << 2))        = acc0[2][smt] + bj02;
            *(float4v*)(pw + (32 + smt * 16 + l) * 20 + (q << 2))   = acc1[2][smt] + bj12;
        }

        // ---- stage W: softmax (unnormalized) + 4-level binary descent ----
        float mW = max16(prW);
        #pragma unroll
        for (int i = 0; i < 16; ++i) prW[i] = __expf(prW[i] - mW);
        float pw0 = prW[0] + prW[1],   pw1 = prW[2] + prW[3];
        float pw2 = prW[4] + prW[5],   pw3 = prW[6] + prW[7];
        float pw4 = prW[8] + prW[9],   pw5 = prW[10] + prW[11];
        float pw6 = prW[12] + prW[13], pw7 = prW[14] + prW[15];
        float qw0 = pw0 + pw1, qw1 = pw2 + pw3, qw2 = pw4 + pw5, qw3 = pw6 + pw7;
        float ow0 = qw0 + qw1, ow1 = qw2 + qw3;
        float sW = ow0 + ow1;
        float ts = tc * sW;                       // search in unnormalized units
        bool b3 = (ts >= ow0);
        float base = b3 ? ow0 : 0.f;
        float qsel = b3 ? qw2 : qw0;
        bool b2 = (ts >= base + qsel);
        base += b2 ? qsel : 0.f;
        float psel = b2 ? (b3 ? pw6 : pw2) : (b3 ? pw4 : pw0);
        bool b1 = (ts >= base + psel);
        base += b1 ? psel : 0.f;
        float eev = b1 ? (b2 ? (b3 ? prW[14] : prW[6]) : (b3 ? prW[10] : prW[2]))
                       : (b2 ? (b3 ? prW[12] : prW[4]) : (b3 ? prW[8]  : prW[0]));
        bool b0 = (ts >= base + eev);
        base += b0 ? eev : 0.f;
        float eod = b1 ? (b2 ? (b3 ? prW[15] : prW[7]) : (b3 ? prW[11] : prW[3]))
                       : (b2 ? (b3 ? prW[13] : prW[5]) : (b3 ? prW[9]  : prW[1]));
        float xkb = base;
        float dxb = b0 ? eod : eev;
        int idx = (b3 ? 8 : 0) + (b2 ? 4 : 0) + (b1 ? 2 : 0) + (b0 ? 1 : 0);

        // ---- D scalar reads: issued as soon as idx is known; latency hides
        //      under stage-H compute below ----
        int i0 = (idx > 0)  ? idx - 1 : 0;
        int i1 = (idx < 15) ? idx     : 14;
        float pa0 = pw[lane * 20 + i0];
        float pa1 = pw[lane * 20 + i1];

        // ---- stage H: softmax (unnormalized); ykb/dyb via descent bits ----
        float mH = max16(prH);
        #pragma unroll
        for (int i = 0; i < 16; ++i) prH[i] = __expf(prH[i] - mH);
        float ph0 = prH[0] + prH[1],   ph1 = prH[2] + prH[3];
        float ph2 = prH[4] + prH[5],   ph3 = prH[6] + prH[7];
        float ph4 = prH[8] + prH[9],   ph5 = prH[10] + prH[11];
        float ph6 = prH[12] + prH[13], ph7 = prH[14] + prH[15];
        float qh0 = ph0 + ph1, qh1 = ph2 + ph3, qh2 = ph4 + ph5, qh3 = ph6 + ph7;
        float oh0 = qh0 + qh1, oh1 = qh2 + qh3;
        float sH = oh0 + oh1;
        float invH = 1.f / sH;
        float qhsel = b3 ? qh2 : qh0;
        float phsel = b2 ? (b3 ? ph6 : ph2) : (b3 ? ph4 : ph0);
        float ehev = b1 ? (b2 ? (b3 ? prH[14] : prH[6]) : (b3 ? prH[10] : prH[2]))
                        : (b2 ? (b3 ? prH[12] : prH[4]) : (b3 ? prH[8]  : prH[0]));
        float ehod = b1 ? (b2 ? (b3 ? prH[15] : prH[7]) : (b3 ? prH[11] : prH[3]))
                        : (b2 ? (b3 ? prH[13] : prH[5]) : (b3 ? prH[9]  : prH[1]));
        float ykb = (b3 ? oh0 : 0.f) + (b2 ? qhsel : 0.f) +
                    (b1 ? phsel : 0.f) + (b0 ? ehev : 0.f);
        float dyb = b0 ? ehod : ehev;

        float d0s = (idx == 0)  ? 1.f : softplus_f(pa0);
        float d1s = (idx == 15) ? 1.f : softplus_f(pa1);

        float rdx = 1.f / dxb;
        float xi  = (ts - xkb) * rdx;        // == (tc - xkb_n)/dxb_n
        float dyn = dyb * invH;
        float ykn = ykb * invH;
        float s   = dyn * sW * rdx;          // (dyb/sH)/(dxb/sW)
        float xim = 1.f - xi;
        float x1m = xi * xim;
        float den = s + (d0s + d1s - 2.f * s) * x1m;
        float rden = 1.f / den;
        float y_in = ykn + dyn * (s * xi * xi + d0s * x1m) * rden;
        float dydx = s * s * (d1s * xi * xi + 2.f * s * x1m + d0s * xim * xim) * (rden * rden);

        yreg[pass] = inb ? y_in : t;
        ld_local += inb ? __logf(dydx) : 0.f;
    }

    // ---- epilogue: y from registers (lane's 8 d's are contiguous); log_det ----
    {
        float4v* o = (float4v*)(out + (size_t)(r0 + row) * 64 + wu * 16 + half * 8);
        o[0] = *(const float4v*)(yreg);
        o[1] = *(const float4v*)(yreg + 4);
    }
    ldp[(wu * 2 + half) * 32 + row] = ld_local;
    __syncthreads();
    if (tid < 32) {
        out[(size_t)N * 64 + r0 + tid] =
            ldp[tid] + ldp[32 + tid] + ldp[64 + tid] + ldp[96 + tid];
    }
}

extern "C" void kernel_launch(void* const* d_in, const int* in_sizes, int n_in,
                              void* d_out, int out_size, void* d_ws, size_t ws_size,
                              hipStream_t stream) {
    const float* x        = (const float*)d_in[0];
    const float* c        = (const float*)d_in[1];
    const float* bn_scale = (const float*)d_in[2];
    const float* bn_bias  = (const float*)d_in[3];
    const float* bn_mean  = (const float*)d_in[4];
    const float* bn_var   = (const float*)d_in[5];
    const float* W0       = (const float*)d_in[6];
    const float* b0       = (const float*)d_in[7];
    const float* W1       = (const float*)d_in[8];
    const float* b1       = (const float*)d_in[9];
    const float* W2       = (const float*)d_in[10];
    const float* b2       = (const float*)d_in[11];
    float* out = (float*)d_out;

    unsigned short* Wt0 = (unsigned short*)d_ws;           // 128*64
    unsigned short* Wt1 = Wt0 + 128 * 64;                  // 128*128
    unsigned short* Wt2 = Wt1 + 128 * 128;                 // 1536*128
    float*          b2p = (float*)(Wt2 + 1536 * 128);      // 32*48
    float*          b0p = b2p + 32 * 48;                   // 128

    const int N = in_sizes[0] / 64;
    prep_weights<<<834, 256, 0, stream>>>(W0, W1, W2, b0, b2,
                                          bn_scale, bn_bias, bn_mean, bn_var,
                                          Wt0, Wt1, Wt2, b0p, b2p);
    nsc_mfma<<<N / ROWS, 128, 0, stream>>>(x, c, Wt0, b0p, Wt1, b1, Wt2, b2p, out, N);
}

// Round 11
// 158.201 us; speedup vs baseline: 1.3264x; 1.3264x over previous
//
#include <hip/hip_runtime.h>
#include <math.h>

#define BN_EPS 1e-5f
#define ROWS 64

typedef __attribute__((ext_vector_type(8))) short short8;
typedef __attribute__((ext_vector_type(4))) float float4v;

__device__ __forceinline__ unsigned short f2bf(float f) {
    union { float f; unsigned int u; } v; v.f = f;
    unsigned int r = v.u + 0x7FFF + ((v.u >> 16) & 1);   // RNE
    return (unsigned short)(r >> 16);
}
__device__ __forceinline__ float softplus_f(float v) {
    float e = __expf(-fabsf(v));
    float r = __logf(1.f + e);
    return v > 0.f ? v + r : r;
}
__device__ __forceinline__ float swish_f(float a) {
    return a / (1.f + __expf(-a));
}

// ---- prep: WIDE elementwise (read-coalesced, write-scatter merged in L2) ----
#define PREP_WIDE_THREADS (1536 * 128 + 128 * 128)   // 212992 -> 832 blocks
__global__ void prep_weights(const float* __restrict__ W0, const float* __restrict__ W1,
                             const float* __restrict__ W2, const float* __restrict__ b0,
                             const float* __restrict__ b2,
                             const float* __restrict__ bn_scale, const float* __restrict__ bn_bias,
                             const float* __restrict__ bn_mean, const float* __restrict__ bn_var,
                             unsigned short* __restrict__ Wt0, unsigned short* __restrict__ Wt1,
                             unsigned short* __restrict__ Wt2, float* __restrict__ b0p,
                             float* __restrict__ b2p) {
    const int bid = blockIdx.x, tid = threadIdx.x;
    if (bid < 832) {
        int i = bid * 256 + tid;
        if (i < 1536 * 128) {
            int k = i / 1536, colp = i - k * 1536;
            int dd = colp / 48, j = colp - dd * 48;
            float v = (j < 47) ? W2[k * 1504 + dd * 47 + j] : 0.f;
            Wt2[(size_t)colp * 128 + k] = f2bf(v);
        } else {
            int i2 = i - 1536 * 128;
            int k = i2 >> 7, n = i2 & 127;
            Wt1[n * 128 + k] = f2bf(W1[k * 128 + n]);
        }
        return;
    }
    if (bid == 832) {
        __shared__ float lds[48 * 129 + 96];
        float* a   = lds + 48 * 129;
        float* bsh = a + 48;
        if (tid < 48) {
            float av = bn_scale[tid] * rsqrtf(bn_var[tid] + BN_EPS);
            a[tid] = av;
            bsh[tid] = bn_bias[tid] - bn_mean[tid] * av;
        }
        for (int idx = tid; idx < 48 * 128; idx += 256) {
            int k = idx >> 7, n = idx & 127;
            lds[k * 129 + n] = W0[k * 128 + n];
        }
        __syncthreads();
        #pragma unroll 4
        for (int it = 0; it < 32; ++it) {
            int n = (tid >> 6) + it * 4;
            int k = tid & 63;
            float v = (k < 48) ? lds[k * 129 + n] * a[k] : 0.f;
            Wt0[n * 64 + k] = f2bf(v);
        }
        if (tid < 128) {
            float s = b0[tid];
            #pragma unroll
            for (int k = 0; k < 48; ++k) s += bsh[k] * lds[k * 129 + tid];
            b0p[tid] = s;
        }
        return;
    }
    for (int e = tid; e < 32 * 48; e += 256) {
        int dd = e / 48, j = e - dd * 48;
        b2p[e] = (j < 47) ? b2[dd * 47 + j] : 0.f;
    }
}

// Round-10 lesson: ROWS=32 halves per-block fixed costs' amortization (weight
// fragment traffic doubles) -> 131us regression. ROWS=64/256t is the floor
// structure (86us, robust to scheduling/VALU/occupancy levers). This version is
// the r9 best + two strictly-subtractive cuts: (a) no-max softmax in W/H
// (exp(p)/sum identical mathematically; |p| << 88 so no overflow; removes the
// depth-4 max tree + 16 subs from the serial path before the exps); (b) the 8
// per-pass t-loads hoisted as two dwordx4 before the pass loop.
__launch_bounds__(256, 4)
__global__ void nsc_mfma(const float* __restrict__ x, const float* __restrict__ c,
                         const unsigned short* __restrict__ Wt0, const float* __restrict__ b0p,
                         const unsigned short* __restrict__ Wt1, const float* __restrict__ b1,
                         const unsigned short* __restrict__ Wt2, const float* __restrict__ b2p,
                         float* __restrict__ out, int N) {
    // region A [0,17408):       h0 [64][72] bf16  ->  h2 [64][136] bf16 (live through GEMM2)
    // region B [17408,38912):   h1 [64][136] bf16 ->  pw 4x[64][20] f32 (20480) + ldp [4][64] f32
    __shared__ __align__(16) char smem[38912];
    unsigned short* h0 = (unsigned short*)smem;            // stride 72
    unsigned short* h2 = (unsigned short*)smem;            // stride 136
    unsigned short* h1 = (unsigned short*)(smem + 17408);  // stride 136
    float*          ldp = (float*)(smem + 17408 + 20480);  // [4][64]

    const int tid  = threadIdx.x;
    const int lane = tid & 63;
    const int l    = lane & 15;
    const int q    = lane >> 4;
    const int wu   = __builtin_amdgcn_readfirstlane(tid >> 6);
    const int r0   = blockIdx.x * ROWS;
    float* pw = (float*)(smem + 17408) + wu * (64 * 20);   // per-wave staging, stride 20

    // ---- phase 1: raw inputs -> h0 bf16 (BN folded into W0); xc passthrough ----
    for (int idx = tid; idx < 64 * 64; idx += 256) {
        int r = idx >> 6, j = idx & 63;
        float h = 0.f;
        if (j < 48) {
            int row = r0 + r;
            h = (j < 32) ? x[(size_t)row * 64 + 32 + j] : c[(size_t)row * 16 + (j - 32)];
        }
        h0[r * 72 + j] = f2bf(h);
    }
    for (int idx = tid; idx < 64 * 8; idx += 256) {
        int r = idx >> 3, ch = idx & 7;
        float4v v = *(const float4v*)(x + (size_t)(r0 + r) * 64 + 32 + ch * 4);
        *(float4v*)(out + (size_t)(r0 + r) * 64 + 32 + ch * 4) = v;
    }
    __syncthreads();

    // ---- phase 2: GEMM0  h1 = swish(h0 @ W0' + b0'), M=64 N=128 K=64(padded) ----
    {
        float4v acc[2][4];
        float4v z = {0.f, 0.f, 0.f, 0.f};
        #pragma unroll
        for (int nt = 0; nt < 2; ++nt)
            #pragma unroll
            for (int mt = 0; mt < 4; ++mt) acc[nt][mt] = z;
        #pragma unroll
        for (int ks = 0; ks < 2; ++ks) {
            short8 a[4];
            #pragma unroll
            for (int mt = 0; mt < 4; ++mt)
                a[mt] = *(const short8*)(h0 + (mt * 16 + l) * 72 + ks * 32 + (q << 3));
            #pragma unroll
            for (int nt = 0; nt < 2; ++nt) {
                int n0 = (wu * 2 + nt) * 16;
                short8 b = *(const short8*)(Wt0 + (n0 + l) * 64 + ks * 32 + (q << 3));
                #pragma unroll
                for (int mt = 0; mt < 4; ++mt)
                    acc[nt][mt] = __builtin_amdgcn_mfma_f32_16x16x32_bf16(a[mt], b, acc[nt][mt], 0, 0, 0);
            }
        }
        #pragma unroll
        for (int nt = 0; nt < 2; ++nt) {
            int n0 = (wu * 2 + nt) * 16;
            float bb = b0p[n0 + l];
            #pragma unroll
            for (int mt = 0; mt < 4; ++mt)
                #pragma unroll
                for (int r = 0; r < 4; ++r)
                    h1[(mt * 16 + q * 4 + r) * 136 + n0 + l] = f2bf(swish_f(acc[nt][mt][r] + bb));
        }
    }
    __syncthreads();

    // ---- phase 3: GEMM1  h2 = swish(h1 @ W1 + b1), M=64 N=128 K=128 ----
    {
        float4v acc[2][4];
        float4v z = {0.f, 0.f, 0.f, 0.f};
        #pragma unroll
        for (int nt = 0; nt < 2; ++nt)
            #pragma unroll
            for (int mt = 0; mt < 4; ++mt) acc[nt][mt] = z;
        #pragma unroll
        for (int ks = 0; ks < 4; ++ks) {
            short8 a[4];
            #pragma unroll
            for (int mt = 0; mt < 4; ++mt)
                a[mt] = *(const short8*)(h1 + (mt * 16 + l) * 136 + ks * 32 + (q << 3));
            #pragma unroll
            for (int nt = 0; nt < 2; ++nt) {
                int n0 = (wu * 2 + nt) * 16;
                short8 b = *(const short8*)(Wt1 + (n0 + l) * 128 + ks * 32 + (q << 3));
                #pragma unroll
                for (int mt = 0; mt < 4; ++mt)
                    acc[nt][mt] = __builtin_amdgcn_mfma_f32_16x16x32_bf16(a[mt], b, acc[nt][mt], 0, 0, 0);
            }
        }
        #pragma unroll
        for (int nt = 0; nt < 2; ++nt) {
            int n0 = (wu * 2 + nt) * 16;
            float bb = b1[n0 + l];
            #pragma unroll
            for (int mt = 0; mt < 4; ++mt)
                #pragma unroll
                for (int r = 0; r < 4; ++r)
                    h2[(mt * 16 + q * 4 + r) * 136 + n0 + l] = f2bf(swish_f(acc[nt][mt][r] + bb));
        }
    }
    __syncthreads();   // h1 dead -> pw reuses region B; h2 live in region A

    // ---- phase 4: GEMM2 (swapped: p^T tiles) + 3-stage spline, descent search ----
    float ld_local = 0.f;
    float yreg[8];
    // all 8 t's for this lane are consecutive floats of one x row: 2 dwordx4
    float tv[8];
    {
        const float* xr = x + (size_t)(r0 + lane) * 64 + wu * 8;
        *(float4v*)(tv)     = *(const float4v*)(xr);
        *(float4v*)(tv + 4) = *(const float4v*)(xr + 4);
    }
    for (int pass = 0; pass < 8; ++pass) {
        const int d = wu * 8 + pass;
        float t = tv[pass];
        float4v bj0 = *(const float4v*)(b2p + d * 48 +      (q << 2));
        float4v bj1 = *(const float4v*)(b2p + d * 48 + 16 + (q << 2));
        float4v bj2 = *(const float4v*)(b2p + d * 48 + 32 + (q << 2));
        bool inb = (t >= 0.f) && (t <= 1.f);
        float tc = fminf(fmaxf(t, 0.f), 1.f);

        float4v acc[3][4];
        float4v z = {0.f, 0.f, 0.f, 0.f};
        #pragma unroll
        for (int jt = 0; jt < 3; ++jt)
            #pragma unroll
            for (int smt = 0; smt < 4; ++smt) acc[jt][smt] = z;
        __builtin_amdgcn_s_setprio(1);
        #pragma unroll
        for (int ks = 0; ks < 4; ++ks) {
            short8 bf[4];
            #pragma unroll
            for (int smt = 0; smt < 4; ++smt)
                bf[smt] = *(const short8*)(h2 + (smt * 16 + l) * 136 + ks * 32 + (q << 3));
            #pragma unroll
            for (int jt = 0; jt < 3; ++jt) {
                short8 a = *(const short8*)(Wt2 + (size_t)(d * 48 + jt * 16 + l) * 128 + ks * 32 + (q << 3));
                #pragma unroll
                for (int smt = 0; smt < 4; ++smt)
                    acc[jt][smt] = __builtin_amdgcn_mfma_f32_16x16x32_bf16(a, bf[smt], acc[jt][smt], 0, 0, 0);
            }
        }
        __builtin_amdgcn_s_setprio(0);

        float prW[16], prH[16];
        // ---- DS burst (per-wave in-order queue): W-write, W-read, H-write,
        //      H-read, D-write all in flight; W-compute overlaps H/D round-trips.
        #pragma unroll
        for (int smt = 0; smt < 4; ++smt)
            *(float4v*)(pw + (smt * 16 + l) * 20 + (q << 2)) = acc[0][smt] + bj0;
        #pragma unroll
        for (int c2 = 0; c2 < 4; ++c2)
            *(float4v*)(prW + c2 * 4) = *(const float4v*)(pw + lane * 20 + c2 * 4);
        #pragma unroll
        for (int smt = 0; smt < 4; ++smt)
            *(float4v*)(pw + (smt * 16 + l) * 20 + (q << 2)) = acc[1][smt] + bj1;
        #pragma unroll
        for (int c2 = 0; c2 < 4; ++c2)
            *(float4v*)(prH + c2 * 4) = *(const float4v*)(pw + lane * 20 + c2 * 4);
        #pragma unroll
        for (int smt = 0; smt < 4; ++smt)
            *(float4v*)(pw + (smt * 16 + l) * 20 + (q << 2)) = acc[2][smt] + bj2;

        // ---- stage W: softmax (no max-shift: |p| bounded, exp safe) + descent ----
        #pragma unroll
        for (int i = 0; i < 16; ++i) prW[i] = __expf(prW[i]);
        float pw0 = prW[0] + prW[1],   pw1 = prW[2] + prW[3];
        float pw2 = prW[4] + prW[5],   pw3 = prW[6] + prW[7];
        float pw4 = prW[8] + prW[9],   pw5 = prW[10] + prW[11];
        float pw6 = prW[12] + prW[13], pw7 = prW[14] + prW[15];
        float qw0 = pw0 + pw1, qw1 = pw2 + pw3, qw2 = pw4 + pw5, qw3 = pw6 + pw7;
        float ow0 = qw0 + qw1, ow1 = qw2 + qw3;
        float sW = ow0 + ow1;
        float ts = tc * sW;                       // search in unnormalized units
        bool b3 = (ts >= ow0);
        float base = b3 ? ow0 : 0.f;
        float qsel = b3 ? qw2 : qw0;
        bool b2 = (ts >= base + qsel);
        base += b2 ? qsel : 0.f;
        float psel = b2 ? (b3 ? pw6 : pw2) : (b3 ? pw4 : pw0);
        bool b1 = (ts >= base + psel);
        base += b1 ? psel : 0.f;
        float eev = b1 ? (b2 ? (b3 ? prW[14] : prW[6]) : (b3 ? prW[10] : prW[2]))
                       : (b2 ? (b3 ? prW[12] : prW[4]) : (b3 ? prW[8]  : prW[0]));
        bool b0 = (ts >= base + eev);
        base += b0 ? eev : 0.f;
        float eod = b1 ? (b2 ? (b3 ? prW[15] : prW[7]) : (b3 ? prW[11] : prW[3]))
                       : (b2 ? (b3 ? prW[13] : prW[5]) : (b3 ? prW[9]  : prW[1]));
        float xkb = base;
        float dxb = b0 ? eod : eev;
        int idx = (b3 ? 8 : 0) + (b2 ? 4 : 0) + (b1 ? 2 : 0) + (b0 ? 1 : 0);

        // ---- D scalar reads: issued as soon as idx is known; latency hides
        //      under stage-H compute below ----
        int i0 = (idx > 0)  ? idx - 1 : 0;
        int i1 = (idx < 15) ? idx     : 14;
        float pa0 = pw[lane * 20 + i0];
        float pa1 = pw[lane * 20 + i1];

        // ---- stage H: softmax (no max-shift); ykb/dyb via descent bits ----
        #pragma unroll
        for (int i = 0; i < 16; ++i) prH[i] = __expf(prH[i]);
        float ph0 = prH[0] + prH[1],   ph1 = prH[2] + prH[3];
        float ph2 = prH[4] + prH[5],   ph3 = prH[6] + prH[7];
        float ph4 = prH[8] + prH[9],   ph5 = prH[10] + prH[11];
        float ph6 = prH[12] + prH[13], ph7 = prH[14] + prH[15];
        float qh0 = ph0 + ph1, qh1 = ph2 + ph3, qh2 = ph4 + ph5, qh3 = ph6 + ph7;
        float oh0 = qh0 + qh1, oh1 = qh2 + qh3;
        float sH = oh0 + oh1;
        float invH = 1.f / sH;
        float qhsel = b3 ? qh2 : qh0;
        float phsel = b2 ? (b3 ? ph6 : ph2) : (b3 ? ph4 : ph0);
        float ehev = b1 ? (b2 ? (b3 ? prH[14] : prH[6]) : (b3 ? prH[10] : prH[2]))
                        : (b2 ? (b3 ? prH[12] : prH[4]) : (b3 ? prH[8]  : prH[0]));
        float ehod = b1 ? (b2 ? (b3 ? prH[15] : prH[7]) : (b3 ? prH[11] : prH[3]))
                        : (b2 ? (b3 ? prH[13] : prH[5]) : (b3 ? prH[9]  : prH[1]));
        float ykb = (b3 ? oh0 : 0.f) + (b2 ? qhsel : 0.f) +
                    (b1 ? phsel : 0.f) + (b0 ? ehev : 0.f);
        float dyb = b0 ? ehod : ehev;

        float d0 = (idx == 0)  ? 1.f : softplus_f(pa0);
        float d1 = (idx == 15) ? 1.f : softplus_f(pa1);

        float rdx = 1.f / dxb;
        float xi  = (ts - xkb) * rdx;        // == (tc - xkb_n)/dxb_n
        float dyn = dyb * invH;
        float ykn = ykb * invH;
        float s   = dyn * sW * rdx;          // (dyb/sH)/(dxb/sW)
        float xim = 1.f - xi;
        float x1m = xi * xim;
        float den = s + (d0 + d1 - 2.f * s) * x1m;
        float rden = 1.f / den;
        float y_in = ykn + dyn * (s * xi * xi + d0 * x1m) * rden;
        float dydx = s * s * (d1 * xi * xi + 2.f * s * x1m + d0 * xim * xim) * (rden * rden);

        yreg[pass] = inb ? y_in : t;
        ld_local += inb ? __logf(dydx) : 0.f;
    }

    // ---- epilogue: y from registers; log_det reduction ----
    {
        float4v* o = (float4v*)(out + (size_t)(r0 + lane) * 64 + wu * 8);
        o[0] = *(const float4v*)(yreg);
        o[1] = *(const float4v*)(yreg + 4);
    }
    ldp[wu * 64 + lane] = ld_local;
    __syncthreads();
    if (tid < 64) {
        out[(size_t)N * 64 + r0 + tid] =
            ldp[tid] + ldp[64 + tid] + ldp[128 + tid] + ldp[192 + tid];
    }
}

extern "C" void kernel_launch(void* const* d_in, const int* in_sizes, int n_in,
                              void* d_out, int out_size, void* d_ws, size_t ws_size,
                              hipStream_t stream) {
    const float* x        = (const float*)d_in[0];
    const float* c        = (const float*)d_in[1];
    const float* bn_scale = (const float*)d_in[2];
    const float* bn_bias  = (const float*)d_in[3];
    const float* bn_mean  = (const float*)d_in[4];
    const float* bn_var   = (const float*)d_in[5];
    const float* W0       = (const float*)d_in[6];
    const float* b0       = (const float*)d_in[7];
    const float* W1       = (const float*)d_in[8];
    const float* b1       = (const float*)d_in[9];
    const float* W2       = (const float*)d_in[10];
    const float* b2       = (const float*)d_in[11];
    float* out = (float*)d_out;

    unsigned short* Wt0 = (unsigned short*)d_ws;           // 128*64
    unsigned short* Wt1 = Wt0 + 128 * 64;                  // 128*128
    unsigned short* Wt2 = Wt1 + 128 * 128;                 // 1536*128
    float*          b2p = (float*)(Wt2 + 1536 * 128);      // 32*48
    float*          b0p = b2p + 32 * 48;                   // 128

    const int N = in_sizes[0] / 64;
    prep_weights<<<834, 256, 0, stream>>>(W0, W1, W2, b0, b2,
                                          bn_scale, bn_bias, bn_mean, bn_var,
                                          Wt0, Wt1, Wt2, b0p, b2p);
    nsc_mfma<<<N / ROWS, 256, 0, stream>>>(x, c, Wt0, b0p, Wt1, b1, Wt2, b2p, out, N);
}

// Round 12
// 156.004 us; speedup vs baseline: 1.3450x; 1.0141x over previous
//
#include <hip/hip_runtime.h>
#include <math.h>

#define BN_EPS 1e-5f
#define ROWS 64

typedef __attribute__((ext_vector_type(8))) short short8;
typedef __attribute__((ext_vector_type(4))) short short4v;
typedef __attribute__((ext_vector_type(4))) float float4v;

__device__ __forceinline__ unsigned short f2bf(float f) {
    union { float f; unsigned int u; } v; v.f = f;
    unsigned int r = v.u + 0x7FFF + ((v.u >> 16) & 1);   // RNE
    return (unsigned short)(r >> 16);
}
__device__ __forceinline__ float softplus_f(float v) {
    float e = __expf(-fabsf(v));
    float r = __logf(1.f + e);
    return v > 0.f ? v + r : r;
}
__device__ __forceinline__ float swish_f(float a) {
    return a / (1.f + __expf(-a));
}

// ---- prep: WIDE elementwise (read-coalesced, write-scatter merged in L2) ----
#define PREP_WIDE_THREADS (1536 * 128 + 128 * 128)   // 212992 -> 832 blocks
__global__ void prep_weights(const float* __restrict__ W0, const float* __restrict__ W1,
                             const float* __restrict__ W2, const float* __restrict__ b0,
                             const float* __restrict__ b2,
                             const float* __restrict__ bn_scale, const float* __restrict__ bn_bias,
                             const float* __restrict__ bn_mean, const float* __restrict__ bn_var,
                             unsigned short* __restrict__ Wt0, unsigned short* __restrict__ Wt1,
                             unsigned short* __restrict__ Wt2, float* __restrict__ b0p,
                             float* __restrict__ b2p) {
    const int bid = blockIdx.x, tid = threadIdx.x;
    if (bid < 832) {
        int i = bid * 256 + tid;
        if (i < 1536 * 128) {
            int k = i / 1536, colp = i - k * 1536;
            int dd = colp / 48, j = colp - dd * 48;
            float v = (j < 47) ? W2[k * 1504 + dd * 47 + j] : 0.f;
            Wt2[(size_t)colp * 128 + k] = f2bf(v);
        } else {
            int i2 = i - 1536 * 128;
            int k = i2 >> 7, n = i2 & 127;
            Wt1[n * 128 + k] = f2bf(W1[k * 128 + n]);
        }
        return;
    }
    if (bid == 832) {
        __shared__ float lds[48 * 129 + 96];
        float* a   = lds + 48 * 129;
        float* bsh = a + 48;
        if (tid < 48) {
            float av = bn_scale[tid] * rsqrtf(bn_var[tid] + BN_EPS);
            a[tid] = av;
            bsh[tid] = bn_bias[tid] - bn_mean[tid] * av;
        }
        for (int idx = tid; idx < 48 * 128; idx += 256) {
            int k = idx >> 7, n = idx & 127;
            lds[k * 129 + n] = W0[k * 128 + n];
        }
        __syncthreads();
        #pragma unroll 4
        for (int it = 0; it < 32; ++it) {
            int n = (tid >> 6) + it * 4;
            int k = tid & 63;
            float v = (k < 48) ? lds[k * 129 + n] * a[k] : 0.f;
            Wt0[n * 64 + k] = f2bf(v);
        }
        if (tid < 128) {
            float s = b0[tid];
            #pragma unroll
            for (int k = 0; k < 48; ++k) s += bsh[k] * lds[k * 129 + tid];
            b0p[tid] = s;
        }
        return;
    }
    for (int e = tid; e < 32 * 48; e += 256) {
        int dd = e / 48, j = e - dd * 48;
        b2p[e] = (j < 47) ? b2[dd * 47 + j] : 0.f;
    }
}

// r11 best (80us) + two subtractive cuts:
// (a) bias-init accumulators: acc[jt][smt][r] corresponds to param jt*16+4q+r,
//     so the bias is constant across smt and l -> init acc to bj instead of 0
//     and DELETE the 12 float4v adds/pass from the post-MFMA DS-burst path.
// (b) vectorized phase 1: float4 loads + 4x f2bf + short4 stores (was 16 scalar
//     branchy iterations/thread).
__launch_bounds__(256, 4)
__global__ void nsc_mfma(const float* __restrict__ x, const float* __restrict__ c,
                         const unsigned short* __restrict__ Wt0, const float* __restrict__ b0p,
                         const unsigned short* __restrict__ Wt1, const float* __restrict__ b1,
                         const unsigned short* __restrict__ Wt2, const float* __restrict__ b2p,
                         float* __restrict__ out, int N) {
    // region A [0,17408):       h0 [64][72] bf16  ->  h2 [64][136] bf16 (live through GEMM2)
    // region B [17408,38912):   h1 [64][136] bf16 ->  pw 4x[64][20] f32 (20480) + ldp [4][64] f32
    __shared__ __align__(16) char smem[38912];
    unsigned short* h0 = (unsigned short*)smem;            // stride 72
    unsigned short* h2 = (unsigned short*)smem;            // stride 136
    unsigned short* h1 = (unsigned short*)(smem + 17408);  // stride 136
    float*          ldp = (float*)(smem + 17408 + 20480);  // [4][64]

    const int tid  = threadIdx.x;
    const int lane = tid & 63;
    const int l    = lane & 15;
    const int q    = lane >> 4;
    const int wu   = __builtin_amdgcn_readfirstlane(tid >> 6);
    const int r0   = blockIdx.x * ROWS;
    float* pw = (float*)(smem + 17408) + wu * (64 * 20);   // per-wave staging, stride 20

    // ---- phase 1: raw inputs -> h0 bf16 (vectorized); xc passthrough ----
    {
        #pragma unroll
        for (int it = 0; it < 4; ++it) {
            int e = tid + it * 256;            // 0..1023
            int r = e >> 4, jb = (e & 15) << 2;
            int row = r0 + r;
            float4v v = {0.f, 0.f, 0.f, 0.f};
            if (jb < 32)       v = *(const float4v*)(x + (size_t)row * 64 + 32 + jb);
            else if (jb < 48)  v = *(const float4v*)(c + (size_t)row * 16 + (jb - 32));
            short4v s;
            s[0] = (short)f2bf(v[0]); s[1] = (short)f2bf(v[1]);
            s[2] = (short)f2bf(v[2]); s[3] = (short)f2bf(v[3]);
            *(short4v*)(h0 + r * 72 + jb) = s;
        }
    }
    for (int idx = tid; idx < 64 * 8; idx += 256) {
        int r = idx >> 3, ch = idx & 7;
        float4v v = *(const float4v*)(x + (size_t)(r0 + r) * 64 + 32 + ch * 4);
        *(float4v*)(out + (size_t)(r0 + r) * 64 + 32 + ch * 4) = v;
    }
    __syncthreads();

    // ---- phase 2: GEMM0  h1 = swish(h0 @ W0' + b0'), M=64 N=128 K=64(padded) ----
    {
        float4v acc[2][4];
        float4v z = {0.f, 0.f, 0.f, 0.f};
        #pragma unroll
        for (int nt = 0; nt < 2; ++nt)
            #pragma unroll
            for (int mt = 0; mt < 4; ++mt) acc[nt][mt] = z;
        #pragma unroll
        for (int ks = 0; ks < 2; ++ks) {
            short8 a[4];
            #pragma unroll
            for (int mt = 0; mt < 4; ++mt)
                a[mt] = *(const short8*)(h0 + (mt * 16 + l) * 72 + ks * 32 + (q << 3));
            #pragma unroll
            for (int nt = 0; nt < 2; ++nt) {
                int n0 = (wu * 2 + nt) * 16;
                short8 b = *(const short8*)(Wt0 + (n0 + l) * 64 + ks * 32 + (q << 3));
                #pragma unroll
                for (int mt = 0; mt < 4; ++mt)
                    acc[nt][mt] = __builtin_amdgcn_mfma_f32_16x16x32_bf16(a[mt], b, acc[nt][mt], 0, 0, 0);
            }
        }
        #pragma unroll
        for (int nt = 0; nt < 2; ++nt) {
            int n0 = (wu * 2 + nt) * 16;
            float bb = b0p[n0 + l];
            #pragma unroll
            for (int mt = 0; mt < 4; ++mt)
                #pragma unroll
                for (int r = 0; r < 4; ++r)
                    h1[(mt * 16 + q * 4 + r) * 136 + n0 + l] = f2bf(swish_f(acc[nt][mt][r] + bb));
        }
    }
    __syncthreads();

    // ---- phase 3: GEMM1  h2 = swish(h1 @ W1 + b1), M=64 N=128 K=128 ----
    {
        float4v acc[2][4];
        float4v z = {0.f, 0.f, 0.f, 0.f};
        #pragma unroll
        for (int nt = 0; nt < 2; ++nt)
            #pragma unroll
            for (int mt = 0; mt < 4; ++mt) acc[nt][mt] = z;
        #pragma unroll
        for (int ks = 0; ks < 4; ++ks) {
            short8 a[4];
            #pragma unroll
            for (int mt = 0; mt < 4; ++mt)
                a[mt] = *(const short8*)(h1 + (mt * 16 + l) * 136 + ks * 32 + (q << 3));
            #pragma unroll
            for (int nt = 0; nt < 2; ++nt) {
                int n0 = (wu * 2 + nt) * 16;
                short8 b = *(const short8*)(Wt1 + (n0 + l) * 128 + ks * 32 + (q << 3));
                #pragma unroll
                for (int mt = 0; mt < 4; ++mt)
                    acc[nt][mt] = __builtin_amdgcn_mfma_f32_16x16x32_bf16(a[mt], b, acc[nt][mt], 0, 0, 0);
            }
        }
        #pragma unroll
        for (int nt = 0; nt < 2; ++nt) {
            int n0 = (wu * 2 + nt) * 16;
            float bb = b1[n0 + l];
            #pragma unroll
            for (int mt = 0; mt < 4; ++mt)
                #pragma unroll
                for (int r = 0; r < 4; ++r)
                    h2[(mt * 16 + q * 4 + r) * 136 + n0 + l] = f2bf(swish_f(acc[nt][mt][r] + bb));
        }
    }
    __syncthreads();   // h1 dead -> pw reuses region B; h2 live in region A

    // ---- phase 4: GEMM2 (swapped: p^T tiles) + 3-stage spline, descent search ----
    float ld_local = 0.f;
    float yreg[8];
    // all 8 t's for this lane are consecutive floats of one x row: 2 dwordx4
    float tv[8];
    {
        const float* xr = x + (size_t)(r0 + lane) * 64 + wu * 8;
        *(float4v*)(tv)     = *(const float4v*)(xr);
        *(float4v*)(tv + 4) = *(const float4v*)(xr + 4);
    }
    for (int pass = 0; pass < 8; ++pass) {
        const int d = wu * 8 + pass;
        float t = tv[pass];
        float4v bj0 = *(const float4v*)(b2p + d * 48 +      (q << 2));
        float4v bj1 = *(const float4v*)(b2p + d * 48 + 16 + (q << 2));
        float4v bj2 = *(const float4v*)(b2p + d * 48 + 32 + (q << 2));
        bool inb = (t >= 0.f) && (t <= 1.f);
        float tc = fminf(fmaxf(t, 0.f), 1.f);

        // bias-init: acc[jt][smt][r] holds param jt*16+4q+r -> C-in = bj_jt
        float4v acc[3][4];
        #pragma unroll
        for (int smt = 0; smt < 4; ++smt) {
            acc[0][smt] = bj0; acc[1][smt] = bj1; acc[2][smt] = bj2;
        }
        __builtin_amdgcn_s_setprio(1);
        #pragma unroll
        for (int ks = 0; ks < 4; ++ks) {
            short8 bf[4];
            #pragma unroll
            for (int smt = 0; smt < 4; ++smt)
                bf[smt] = *(const short8*)(h2 + (smt * 16 + l) * 136 + ks * 32 + (q << 3));
            #pragma unroll
            for (int jt = 0; jt < 3; ++jt) {
                short8 a = *(const short8*)(Wt2 + (size_t)(d * 48 + jt * 16 + l) * 128 + ks * 32 + (q << 3));
                #pragma unroll
                for (int smt = 0; smt < 4; ++smt)
                    acc[jt][smt] = __builtin_amdgcn_mfma_f32_16x16x32_bf16(a, bf[smt], acc[jt][smt], 0, 0, 0);
            }
        }
        __builtin_amdgcn_s_setprio(0);

        float prW[16], prH[16];
        // ---- DS burst (per-wave in-order queue): W-write, W-read, H-write,
        //      H-read, D-write all in flight; W-compute overlaps H/D round-trips.
        #pragma unroll
        for (int smt = 0; smt < 4; ++smt)
            *(float4v*)(pw + (smt * 16 + l) * 20 + (q << 2)) = acc[0][smt];
        #pragma unroll
        for (int c2 = 0; c2 < 4; ++c2)
            *(float4v*)(prW + c2 * 4) = *(const float4v*)(pw + lane * 20 + c2 * 4);
        #pragma unroll
        for (int smt = 0; smt < 4; ++smt)
            *(float4v*)(pw + (smt * 16 + l) * 20 + (q << 2)) = acc[1][smt];
        #pragma unroll
        for (int c2 = 0; c2 < 4; ++c2)
            *(float4v*)(prH + c2 * 4) = *(const float4v*)(pw + lane * 20 + c2 * 4);
        #pragma unroll
        for (int smt = 0; smt < 4; ++smt)
            *(float4v*)(pw + (smt * 16 + l) * 20 + (q << 2)) = acc[2][smt];

        // ---- stage W: softmax (no max-shift: |p| bounded, exp safe) + descent ----
        #pragma unroll
        for (int i = 0; i < 16; ++i) prW[i] = __expf(prW[i]);
        float pw0 = prW[0] + prW[1],   pw1 = prW[2] + prW[3];
        float pw2 = prW[4] + prW[5],   pw3 = prW[6] + prW[7];
        float pw4 = prW[8] + prW[9],   pw5 = prW[10] + prW[11];
        float pw6 = prW[12] + prW[13], pw7 = prW[14] + prW[15];
        float qw0 = pw0 + pw1, qw1 = pw2 + pw3, qw2 = pw4 + pw5, qw3 = pw6 + pw7;
        float ow0 = qw0 + qw1, ow1 = qw2 + qw3;
        float sW = ow0 + ow1;
        float ts = tc * sW;                       // search in unnormalized units
        bool b3 = (ts >= ow0);
        float base = b3 ? ow0 : 0.f;
        float qsel = b3 ? qw2 : qw0;
        bool b2 = (ts >= base + qsel);
        base += b2 ? qsel : 0.f;
        float psel = b2 ? (b3 ? pw6 : pw2) : (b3 ? pw4 : pw0);
        bool b1 = (ts >= base + psel);
        base += b1 ? psel : 0.f;
        float eev = b1 ? (b2 ? (b3 ? prW[14] : prW[6]) : (b3 ? prW[10] : prW[2]))
                       : (b2 ? (b3 ? prW[12] : prW[4]) : (b3 ? prW[8]  : prW[0]));
        bool b0 = (ts >= base + eev);
        base += b0 ? eev : 0.f;
        float eod = b1 ? (b2 ? (b3 ? prW[15] : prW[7]) : (b3 ? prW[11] : prW[3]))
                       : (b2 ? (b3 ? prW[13] : prW[5]) : (b3 ? prW[9]  : prW[1]));
        float xkb = base;
        float dxb = b0 ? eod : eev;
        int idx = (b3 ? 8 : 0) + (b2 ? 4 : 0) + (b1 ? 2 : 0) + (b0 ? 1 : 0);

        // ---- D scalar reads: issued as soon as idx is known; latency hides
        //      under stage-H compute below ----
        int i0 = (idx > 0)  ? idx - 1 : 0;
        int i1 = (idx < 15) ? idx     : 14;
        float pa0 = pw[lane * 20 + i0];
        float pa1 = pw[lane * 20 + i1];

        // ---- stage H: softmax (no max-shift); ykb/dyb via descent bits ----
        #pragma unroll
        for (int i = 0; i < 16; ++i) prH[i] = __expf(prH[i]);
        float ph0 = prH[0] + prH[1],   ph1 = prH[2] + prH[3];
        float ph2 = prH[4] + prH[5],   ph3 = prH[6] + prH[7];
        float ph4 = prH[8] + prH[9],   ph5 = prH[10] + prH[11];
        float ph6 = prH[12] + prH[13], ph7 = prH[14] + prH[15];
        float qh0 = ph0 + ph1, qh1 = ph2 + ph3, qh2 = ph4 + ph5, qh3 = ph6 + ph7;
        float oh0 = qh0 + qh1, oh1 = qh2 + qh3;
        float sH = oh0 + oh1;
        float invH = 1.f / sH;
        float qhsel = b3 ? qh2 : qh0;
        float phsel = b2 ? (b3 ? ph6 : ph2) : (b3 ? ph4 : ph0);
        float ehev = b1 ? (b2 ? (b3 ? prH[14] : prH[6]) : (b3 ? prH[10] : prH[2]))
                        : (b2 ? (b3 ? prH[12] : prH[4]) : (b3 ? prH[8]  : prH[0]));
        float ehod = b1 ? (b2 ? (b3 ? prH[15] : prH[7]) : (b3 ? prH[11] : prH[3]))
                        : (b2 ? (b3 ? prH[13] : prH[5]) : (b3 ? prH[9]  : prH[1]));
        float ykb = (b3 ? oh0 : 0.f) + (b2 ? qhsel : 0.f) +
                    (b1 ? phsel : 0.f) + (b0 ? ehev : 0.f);
        float dyb = b0 ? ehod : ehev;

        float d0 = (idx == 0)  ? 1.f : softplus_f(pa0);
        float d1 = (idx == 15) ? 1.f : softplus_f(pa1);

        float rdx = 1.f / dxb;
        float xi  = (ts - xkb) * rdx;        // == (tc - xkb_n)/dxb_n
        float dyn = dyb * invH;
        float ykn = ykb * invH;
        float s   = dyn * sW * rdx;          // (dyb/sH)/(dxb/sW)
        float xim = 1.f - xi;
        float x1m = xi * xim;
        float den = s + (d0 + d1 - 2.f * s) * x1m;
        float rden = 1.f / den;
        float y_in = ykn + dyn * (s * xi * xi + d0 * x1m) * rden;
        float dydx = s * s * (d1 * xi * xi + 2.f * s * x1m + d0 * xim * xim) * (rden * rden);

        yreg[pass] = inb ? y_in : t;
        ld_local += inb ? __logf(dydx) : 0.f;
    }

    // ---- epilogue: y from registers; log_det reduction ----
    {
        float4v* o = (float4v*)(out + (size_t)(r0 + lane) * 64 + wu * 8);
        o[0] = *(const float4v*)(yreg);
        o[1] = *(const float4v*)(yreg + 4);
    }
    ldp[wu * 64 + lane] = ld_local;
    __syncthreads();
    if (tid < 64) {
        out[(size_t)N * 64 + r0 + tid] =
            ldp[tid] + ldp[64 + tid] + ldp[128 + tid] + ldp[192 + tid];
    }
}

extern "C" void kernel_launch(void* const* d_in, const int* in_sizes, int n_in,
                              void* d_out, int out_size, void* d_ws, size_t ws_size,
                              hipStream_t stream) {
    const float* x        = (const float*)d_in[0];
    const float* c        = (const float*)d_in[1];
    const float* bn_scale = (const float*)d_in[2];
    const float* bn_bias  = (const float*)d_in[3];
    const float* bn_mean  = (const float*)d_in[4];
    const float* bn_var   = (const float*)d_in[5];
    const float* W0       = (const float*)d_in[6];
    const float* b0       = (const float*)d_in[7];
    const float* W1       = (const float*)d_in[8];
    const float* b1       = (const float*)d_in[9];
    const float* W2       = (const float*)d_in[10];
    const float* b2       = (const float*)d_in[11];
    float* out = (float*)d_out;

    unsigned short* Wt0 = (unsigned short*)d_ws;           // 128*64
    unsigned short* Wt1 = Wt0 + 128 * 64;                  // 128*128
    unsigned short* Wt2 = Wt1 + 128 * 128;                 // 1536*128
    float*          b2p = (float*)(Wt2 + 1536 * 128);      // 32*48
    float*          b0p = b2p + 32 * 48;                   // 128

    const int N = in_sizes[0] / 64;
    prep_weights<<<834, 256, 0, stream>>>(W0, W1, W2, b0, b2,
                                          bn_scale, bn_bias, bn_mean, bn_var,
                                          Wt0, Wt1, Wt2, b0p, b2p);
    nsc_mfma<<<N / ROWS, 256, 0, stream>>>(x, c, Wt0, b0p, Wt1, b1, Wt2, b2p, out, N);
}

// Round 13
// 150.722 us; speedup vs baseline: 1.3922x; 1.0350x over previous
//
#include <hip/hip_runtime.h>
#include <math.h>

#define BN_EPS 1e-5f
#define ROWS 64

typedef __attribute__((ext_vector_type(8))) short short8;
typedef __attribute__((ext_vector_type(4))) short short4v;
typedef __attribute__((ext_vector_type(4))) float float4v;

__device__ __forceinline__ unsigned short f2bf(float f) {
    union { float f; unsigned int u; } v; v.f = f;
    unsigned int r = v.u + 0x7FFF + ((v.u >> 16) & 1);   // RNE
    return (unsigned short)(r >> 16);
}
// 1-ulp reciprocal (v_rcp_f32). Avoids the ~8-op IEEE div sequence the
// compiler emits for a/b without fast-math. All denominators here are
// positive, normal-range -> safe.
__device__ __forceinline__ float rcp_f(float v) {
    float r; asm("v_rcp_f32 %0, %1" : "=v"(r) : "v"(v)); return r;
}
__device__ __forceinline__ float softplus_f(float v) {
    float e = __expf(-fabsf(v));
    float r = __logf(1.f + e);
    return v > 0.f ? v + r : r;
}
__device__ __forceinline__ float swish_f(float a) {
    return a * rcp_f(1.f + __expf(-a));
}

// ---- prep: WIDE elementwise (read-coalesced, write-scatter merged in L2) ----
#define PREP_WIDE_THREADS (1536 * 128 + 128 * 128)   // 212992 -> 832 blocks
__global__ void prep_weights(const float* __restrict__ W0, const float* __restrict__ W1,
                             const float* __restrict__ W2, const float* __restrict__ b0,
                             const float* __restrict__ b2,
                             const float* __restrict__ bn_scale, const float* __restrict__ bn_bias,
                             const float* __restrict__ bn_mean, const float* __restrict__ bn_var,
                             unsigned short* __restrict__ Wt0, unsigned short* __restrict__ Wt1,
                             unsigned short* __restrict__ Wt2, float* __restrict__ b0p,
                             float* __restrict__ b2p) {
    const int bid = blockIdx.x, tid = threadIdx.x;
    if (bid < 832) {
        int i = bid * 256 + tid;
        if (i < 1536 * 128) {
            int k = i / 1536, colp = i - k * 1536;
            int dd = colp / 48, j = colp - dd * 48;
            float v = (j < 47) ? W2[k * 1504 + dd * 47 + j] : 0.f;
            Wt2[(size_t)colp * 128 + k] = f2bf(v);
        } else {
            int i2 = i - 1536 * 128;
            int k = i2 >> 7, n = i2 & 127;
            Wt1[n * 128 + k] = f2bf(W1[k * 128 + n]);
        }
        return;
    }
    if (bid == 832) {
        __shared__ float lds[48 * 129 + 96];
        float* a   = lds + 48 * 129;
        float* bsh = a + 48;
        if (tid < 48) {
            float av = bn_scale[tid] * rsqrtf(bn_var[tid] + BN_EPS);
            a[tid] = av;
            bsh[tid] = bn_bias[tid] - bn_mean[tid] * av;
        }
        for (int idx = tid; idx < 48 * 128; idx += 256) {
            int k = idx >> 7, n = idx & 127;
            lds[k * 129 + n] = W0[k * 128 + n];
        }
        __syncthreads();
        #pragma unroll 4
        for (int it = 0; it < 32; ++it) {
            int n = (tid >> 6) + it * 4;
            int k = tid & 63;
            float v = (k < 48) ? lds[k * 129 + n] * a[k] : 0.f;
            Wt0[n * 64 + k] = f2bf(v);
        }
        if (tid < 128) {
            float s = b0[tid];
            #pragma unroll
            for (int k = 0; k < 48; ++k) s += bsh[k] * lds[k * 129 + tid];
            b0p[tid] = s;
        }
        return;
    }
    for (int e = tid; e < 32 * 48; e += 256) {
        int dd = e / 48, j = e - dd * 48;
        b2p[e] = (j < 47) ? b2[dd * 47 + j] : 0.f;
    }
}

// r12 best (76us) + fast-reciprocal cut: without -ffast-math every float div
// is a ~8-op IEEE sequence. swish (64x/thread) and phase-4's rdx/invH/rden
// (24x/thread, on the serial path) now use v_rcp_f32 + mul. ~550 VALU
// ops/thread deleted; phase-4 serial depth -20cy/pass. 1-ulp rcp is invisible
// vs the bf16-dominated 0.28 absmax.
__launch_bounds__(256, 4)
__global__ void nsc_mfma(const float* __restrict__ x, const float* __restrict__ c,
                         const unsigned short* __restrict__ Wt0, const float* __restrict__ b0p,
                         const unsigned short* __restrict__ Wt1, const float* __restrict__ b1,
                         const unsigned short* __restrict__ Wt2, const float* __restrict__ b2p,
                         float* __restrict__ out, int N) {
    // region A [0,17408):       h0 [64][72] bf16  ->  h2 [64][136] bf16 (live through GEMM2)
    // region B [17408,38912):   h1 [64][136] bf16 ->  pw 4x[64][20] f32 (20480) + ldp [4][64] f32
    __shared__ __align__(16) char smem[38912];
    unsigned short* h0 = (unsigned short*)smem;            // stride 72
    unsigned short* h2 = (unsigned short*)smem;            // stride 136
    unsigned short* h1 = (unsigned short*)(smem + 17408);  // stride 136
    float*          ldp = (float*)(smem + 17408 + 20480);  // [4][64]

    const int tid  = threadIdx.x;
    const int lane = tid & 63;
    const int l    = lane & 15;
    const int q    = lane >> 4;
    const int wu   = __builtin_amdgcn_readfirstlane(tid >> 6);
    const int r0   = blockIdx.x * ROWS;
    float* pw = (float*)(smem + 17408) + wu * (64 * 20);   // per-wave staging, stride 20

    // ---- phase 1: raw inputs -> h0 bf16 (vectorized); xc passthrough ----
    {
        #pragma unroll
        for (int it = 0; it < 4; ++it) {
            int e = tid + it * 256;            // 0..1023
            int r = e >> 4, jb = (e & 15) << 2;
            int row = r0 + r;
            float4v v = {0.f, 0.f, 0.f, 0.f};
            if (jb < 32)       v = *(const float4v*)(x + (size_t)row * 64 + 32 + jb);
            else if (jb < 48)  v = *(const float4v*)(c + (size_t)row * 16 + (jb - 32));
            short4v s;
            s[0] = (short)f2bf(v[0]); s[1] = (short)f2bf(v[1]);
            s[2] = (short)f2bf(v[2]); s[3] = (short)f2bf(v[3]);
            *(short4v*)(h0 + r * 72 + jb) = s;
        }
    }
    for (int idx = tid; idx < 64 * 8; idx += 256) {
        int r = idx >> 3, ch = idx & 7;
        float4v v = *(const float4v*)(x + (size_t)(r0 + r) * 64 + 32 + ch * 4);
        *(float4v*)(out + (size_t)(r0 + r) * 64 + 32 + ch * 4) = v;
    }
    __syncthreads();

    // ---- phase 2: GEMM0  h1 = swish(h0 @ W0' + b0'), M=64 N=128 K=64(padded) ----
    {
        float4v acc[2][4];
        float4v z = {0.f, 0.f, 0.f, 0.f};
        #pragma unroll
        for (int nt = 0; nt < 2; ++nt)
            #pragma unroll
            for (int mt = 0; mt < 4; ++mt) acc[nt][mt] = z;
        #pragma unroll
        for (int ks = 0; ks < 2; ++ks) {
            short8 a[4];
            #pragma unroll
            for (int mt = 0; mt < 4; ++mt)
                a[mt] = *(const short8*)(h0 + (mt * 16 + l) * 72 + ks * 32 + (q << 3));
            #pragma unroll
            for (int nt = 0; nt < 2; ++nt) {
                int n0 = (wu * 2 + nt) * 16;
                short8 b = *(const short8*)(Wt0 + (n0 + l) * 64 + ks * 32 + (q << 3));
                #pragma unroll
                for (int mt = 0; mt < 4; ++mt)
                    acc[nt][mt] = __builtin_amdgcn_mfma_f32_16x16x32_bf16(a[mt], b, acc[nt][mt], 0, 0, 0);
            }
        }
        #pragma unroll
        for (int nt = 0; nt < 2; ++nt) {
            int n0 = (wu * 2 + nt) * 16;
            float bb = b0p[n0 + l];
            #pragma unroll
            for (int mt = 0; mt < 4; ++mt)
                #pragma unroll
                for (int r = 0; r < 4; ++r)
                    h1[(mt * 16 + q * 4 + r) * 136 + n0 + l] = f2bf(swish_f(acc[nt][mt][r] + bb));
        }
    }
    __syncthreads();

    // ---- phase 3: GEMM1  h2 = swish(h1 @ W1 + b1), M=64 N=128 K=128 ----
    {
        float4v acc[2][4];
        float4v z = {0.f, 0.f, 0.f, 0.f};
        #pragma unroll
        for (int nt = 0; nt < 2; ++nt)
            #pragma unroll
            for (int mt = 0; mt < 4; ++mt) acc[nt][mt] = z;
        #pragma unroll
        for (int ks = 0; ks < 4; ++ks) {
            short8 a[4];
            #pragma unroll
            for (int mt = 0; mt < 4; ++mt)
                a[mt] = *(const short8*)(h1 + (mt * 16 + l) * 136 + ks * 32 + (q << 3));
            #pragma unroll
            for (int nt = 0; nt < 2; ++nt) {
                int n0 = (wu * 2 + nt) * 16;
                short8 b = *(const short8*)(Wt1 + (n0 + l) * 128 + ks * 32 + (q << 3));
                #pragma unroll
                for (int mt = 0; mt < 4; ++mt)
                    acc[nt][mt] = __builtin_amdgcn_mfma_f32_16x16x32_bf16(a[mt], b, acc[nt][mt], 0, 0, 0);
            }
        }
        #pragma unroll
        for (int nt = 0; nt < 2; ++nt) {
            int n0 = (wu * 2 + nt) * 16;
            float bb = b1[n0 + l];
            #pragma unroll
            for (int mt = 0; mt < 4; ++mt)
                #pragma unroll
                for (int r = 0; r < 4; ++r)
                    h2[(mt * 16 + q * 4 + r) * 136 + n0 + l] = f2bf(swish_f(acc[nt][mt][r] + bb));
        }
    }
    __syncthreads();   // h1 dead -> pw reuses region B; h2 live in region A

    // ---- phase 4: GEMM2 (swapped: p^T tiles) + 3-stage spline, descent search ----
    float ld_local = 0.f;
    float yreg[8];
    // all 8 t's for this lane are consecutive floats of one x row: 2 dwordx4
    float tv[8];
    {
        const float* xr = x + (size_t)(r0 + lane) * 64 + wu * 8;
        *(float4v*)(tv)     = *(const float4v*)(xr);
        *(float4v*)(tv + 4) = *(const float4v*)(xr + 4);
    }
    for (int pass = 0; pass < 8; ++pass) {
        const int d = wu * 8 + pass;
        float t = tv[pass];
        float4v bj0 = *(const float4v*)(b2p + d * 48 +      (q << 2));
        float4v bj1 = *(const float4v*)(b2p + d * 48 + 16 + (q << 2));
        float4v bj2 = *(const float4v*)(b2p + d * 48 + 32 + (q << 2));
        bool inb = (t >= 0.f) && (t <= 1.f);
        float tc = fminf(fmaxf(t, 0.f), 1.f);

        // bias-init: acc[jt][smt][r] holds param jt*16+4q+r -> C-in = bj_jt
        float4v acc[3][4];
        #pragma unroll
        for (int smt = 0; smt < 4; ++smt) {
            acc[0][smt] = bj0; acc[1][smt] = bj1; acc[2][smt] = bj2;
        }
        __builtin_amdgcn_s_setprio(1);
        #pragma unroll
        for (int ks = 0; ks < 4; ++ks) {
            short8 bf[4];
            #pragma unroll
            for (int smt = 0; smt < 4; ++smt)
                bf[smt] = *(const short8*)(h2 + (smt * 16 + l) * 136 + ks * 32 + (q << 3));
            #pragma unroll
            for (int jt = 0; jt < 3; ++jt) {
                short8 a = *(const short8*)(Wt2 + (size_t)(d * 48 + jt * 16 + l) * 128 + ks * 32 + (q << 3));
                #pragma unroll
                for (int smt = 0; smt < 4; ++smt)
                    acc[jt][smt] = __builtin_amdgcn_mfma_f32_16x16x32_bf16(a, bf[smt], acc[jt][smt], 0, 0, 0);
            }
        }
        __builtin_amdgcn_s_setprio(0);

        float prW[16], prH[16];
        // ---- DS burst (per-wave in-order queue): W-write, W-read, H-write,
        //      H-read, D-write all in flight; W-compute overlaps H/D round-trips.
        #pragma unroll
        for (int smt = 0; smt < 4; ++smt)
            *(float4v*)(pw + (smt * 16 + l) * 20 + (q << 2)) = acc[0][smt];
        #pragma unroll
        for (int c2 = 0; c2 < 4; ++c2)
            *(float4v*)(prW + c2 * 4) = *(const float4v*)(pw + lane * 20 + c2 * 4);
        #pragma unroll
        for (int smt = 0; smt < 4; ++smt)
            *(float4v*)(pw + (smt * 16 + l) * 20 + (q << 2)) = acc[1][smt];
        #pragma unroll
        for (int c2 = 0; c2 < 4; ++c2)
            *(float4v*)(prH + c2 * 4) = *(const float4v*)(pw + lane * 20 + c2 * 4);
        #pragma unroll
        for (int smt = 0; smt < 4; ++smt)
            *(float4v*)(pw + (smt * 16 + l) * 20 + (q << 2)) = acc[2][smt];

        // ---- stage W: softmax (no max-shift: |p| bounded, exp safe) + descent ----
        #pragma unroll
        for (int i = 0; i < 16; ++i) prW[i] = __expf(prW[i]);
        float pw0 = prW[0] + prW[1],   pw1 = prW[2] + prW[3];
        float pw2 = prW[4] + prW[5],   pw3 = prW[6] + prW[7];
        float pw4 = prW[8] + prW[9],   pw5 = prW[10] + prW[11];
        float pw6 = prW[12] + prW[13], pw7 = prW[14] + prW[15];
        float qw0 = pw0 + pw1, qw1 = pw2 + pw3, qw2 = pw4 + pw5, qw3 = pw6 + pw7;
        float ow0 = qw0 + qw1, ow1 = qw2 + qw3;
        float sW = ow0 + ow1;
        float ts = tc * sW;                       // search in unnormalized units
        bool b3 = (ts >= ow0);
        float base = b3 ? ow0 : 0.f;
        float qsel = b3 ? qw2 : qw0;
        bool b2 = (ts >= base + qsel);
        base += b2 ? qsel : 0.f;
        float psel = b2 ? (b3 ? pw6 : pw2) : (b3 ? pw4 : pw0);
        bool b1 = (ts >= base + psel);
        base += b1 ? psel : 0.f;
        float eev = b1 ? (b2 ? (b3 ? prW[14] : prW[6]) : (b3 ? prW[10] : prW[2]))
                       : (b2 ? (b3 ? prW[12] : prW[4]) : (b3 ? prW[8]  : prW[0]));
        bool b0 = (ts >= base + eev);
        base += b0 ? eev : 0.f;
        float eod = b1 ? (b2 ? (b3 ? prW[15] : prW[7]) : (b3 ? prW[11] : prW[3]))
                       : (b2 ? (b3 ? prW[13] : prW[5]) : (b3 ? prW[9]  : prW[1]));
        float xkb = base;
        float dxb = b0 ? eod : eev;
        int idx = (b3 ? 8 : 0) + (b2 ? 4 : 0) + (b1 ? 2 : 0) + (b0 ? 1 : 0);

        // ---- D scalar reads: issued as soon as idx is known; latency hides
        //      under stage-H compute below ----
        int i0 = (idx > 0)  ? idx - 1 : 0;
        int i1 = (idx < 15) ? idx     : 14;
        float pa0 = pw[lane * 20 + i0];
        float pa1 = pw[lane * 20 + i1];

        // ---- stage H: softmax (no max-shift); ykb/dyb via descent bits ----
        #pragma unroll
        for (int i = 0; i < 16; ++i) prH[i] = __expf(prH[i]);
        float ph0 = prH[0] + prH[1],   ph1 = prH[2] + prH[3];
        float ph2 = prH[4] + prH[5],   ph3 = prH[6] + prH[7];
        float ph4 = prH[8] + prH[9],   ph5 = prH[10] + prH[11];
        float ph6 = prH[12] + prH[13], ph7 = prH[14] + prH[15];
        float qh0 = ph0 + ph1, qh1 = ph2 + ph3, qh2 = ph4 + ph5, qh3 = ph6 + ph7;
        float oh0 = qh0 + qh1, oh1 = qh2 + qh3;
        float sH = oh0 + oh1;
        float invH = rcp_f(sH);
        float qhsel = b3 ? qh2 : qh0;
        float phsel = b2 ? (b3 ? ph6 : ph2) : (b3 ? ph4 : ph0);
        float ehev = b1 ? (b2 ? (b3 ? prH[14] : prH[6]) : (b3 ? prH[10] : prH[2]))
                        : (b2 ? (b3 ? prH[12] : prH[4]) : (b3 ? prH[8]  : prH[0]));
        float ehod = b1 ? (b2 ? (b3 ? prH[15] : prH[7]) : (b3 ? prH[11] : prH[3]))
                        : (b2 ? (b3 ? prH[13] : prH[5]) : (b3 ? prH[9]  : prH[1]));
        float ykb = (b3 ? oh0 : 0.f) + (b2 ? qhsel : 0.f) +
                    (b1 ? phsel : 0.f) + (b0 ? ehev : 0.f);
        float dyb = b0 ? ehod : ehev;

        float d0 = (idx == 0)  ? 1.f : softplus_f(pa0);
        float d1 = (idx == 15) ? 1.f : softplus_f(pa1);

        float rdx = rcp_f(dxb);
        float xi  = (ts - xkb) * rdx;        // == (tc - xkb_n)/dxb_n
        float dyn = dyb * invH;
        float ykn = ykb * invH;
        float s   = dyn * sW * rdx;          // (dyb/sH)/(dxb/sW)
        float xim = 1.f - xi;
        float x1m = xi * xim;
        float den = s + (d0 + d1 - 2.f * s) * x1m;
        float rden = rcp_f(den);
        float y_in = ykn + dyn * (s * xi * xi + d0 * x1m) * rden;
        float dydx = s * s * (d1 * xi * xi + 2.f * s * x1m + d0 * xim * xim) * (rden * rden);

        yreg[pass] = inb ? y_in : t;
        ld_local += inb ? __logf(dydx) : 0.f;
    }

    // ---- epilogue: y from registers; log_det reduction ----
    {
        float4v* o = (float4v*)(out + (size_t)(r0 + lane) * 64 + wu * 8);
        o[0] = *(const float4v*)(yreg);
        o[1] = *(const float4v*)(yreg + 4);
    }
    ldp[wu * 64 + lane] = ld_local;
    __syncthreads();
    if (tid < 64) {
        out[(size_t)N * 64 + r0 + tid] =
            ldp[tid] + ldp[64 + tid] + ldp[128 + tid] + ldp[192 + tid];
    }
}

extern "C" void kernel_launch(void* const* d_in, const int* in_sizes, int n_in,
                              void* d_out, int out_size, void* d_ws, size_t ws_size,
                              hipStream_t stream) {
    const float* x        = (const float*)d_in[0];
    const float* c        = (const float*)d_in[1];
    const float* bn_scale = (const float*)d_in[2];
    const float* bn_bias  = (const float*)d_in[3];
    const float* bn_mean  = (const float*)d_in[4];
    const float* bn_var   = (const float*)d_in[5];
    const float* W0       = (const float*)d_in[6];
    const float* b0       = (const float*)d_in[7];
    const float* W1       = (const float*)d_in[8];
    const float* b1       = (const float*)d_in[9];
    const float* W2       = (const float*)d_in[10];
    const float* b2       = (const float*)d_in[11];
    float* out = (float*)d_out;

    unsigned short* Wt0 = (unsigned short*)d_ws;           // 128*64
    unsigned short* Wt1 = Wt0 + 128 * 64;                  // 128*128
    unsigned short* Wt2 = Wt1 + 128 * 128;                 // 1536*128
    float*          b2p = (float*)(Wt2 + 1536 * 128);      // 32*48
    float*          b0p = b2p + 32 * 48;                   // 128

    const int N = in_sizes[0] / 64;
    prep_weights<<<834, 256, 0, stream>>>(W0, W1, W2, b0, b2,
                                          bn_scale, bn_bias, bn_mean, bn_var,
                                          Wt0, Wt1, Wt2, b0p, b2p);
    nsc_mfma<<<N / ROWS, 256, 0, stream>>>(x, c, Wt0, b0p, Wt1, b1, Wt2, b2p, out, N);
}

// Round 14
// 150.016 us; speedup vs baseline: 1.3987x; 1.0047x over previous
//
#include <hip/hip_runtime.h>
#include <math.h>

#define BN_EPS 1e-5f
#define ROWS 64
#define LOG2E 1.44269504088896f
#define LN2   0.693147180559945f

typedef __attribute__((ext_vector_type(8))) short short8;
typedef __attribute__((ext_vector_type(4))) short short4v;
typedef __attribute__((ext_vector_type(4))) float float4v;

__device__ __forceinline__ unsigned short f2bf(float f) {
    union { float f; unsigned int u; } v; v.f = f;
    unsigned int r = v.u + 0x7FFF + ((v.u >> 16) & 1);   // RNE
    return (unsigned short)(r >> 16);
}
// 1-ulp hardware ops (avoid IEEE div sequence / libm wrappers).
__device__ __forceinline__ float rcp_f(float v) {
    float r; asm("v_rcp_f32 %0, %1" : "=v"(r) : "v"(v)); return r;
}
__device__ __forceinline__ float exp2_f(float v) {      // v_exp_f32 IS 2^x
    float r; asm("v_exp_f32 %0, %1" : "=v"(r) : "v"(v)); return r;
}
__device__ __forceinline__ float log2_f(float v) {      // v_log_f32 IS log2
    float r; asm("v_log_f32 %0, %1" : "=v"(r) : "v"(v)); return r;
}
__device__ __forceinline__ float softplus_f(float v) {
    float e = __expf(-fabsf(v));
    float r = __logf(1.f + e);
    return v > 0.f ? v + r : r;
}
__device__ __forceinline__ float swish_f(float a) {
    return a * rcp_f(1.f + __expf(-a));
}

// ---- prep: WIDE elementwise (read-coalesced, write-scatter merged in L2) ----
// W/H param rows (j<32) are pre-scaled by log2(e) so the kernel's softmaxes
// use raw v_exp_f32 (2^x) with no per-element mul. D rows stay raw (softplus).
#define PREP_WIDE_THREADS (1536 * 128 + 128 * 128)   // 212992 -> 832 blocks
__global__ void prep_weights(const float* __restrict__ W0, const float* __restrict__ W1,
                             const float* __restrict__ W2, const float* __restrict__ b0,
                             const float* __restrict__ b2,
                             const float* __restrict__ bn_scale, const float* __restrict__ bn_bias,
                             const float* __restrict__ bn_mean, const float* __restrict__ bn_var,
                             unsigned short* __restrict__ Wt0, unsigned short* __restrict__ Wt1,
                             unsigned short* __restrict__ Wt2, float* __restrict__ b0p,
                             float* __restrict__ b2p) {
    const int bid = blockIdx.x, tid = threadIdx.x;
    if (bid < 832) {
        int i = bid * 256 + tid;
        if (i < 1536 * 128) {
            int k = i / 1536, colp = i - k * 1536;
            int dd = colp / 48, j = colp - dd * 48;
            float v = (j < 47) ? W2[k * 1504 + dd * 47 + j] : 0.f;
            if (j < 32) v *= LOG2E;
            Wt2[(size_t)colp * 128 + k] = f2bf(v);
        } else {
            int i2 = i - 1536 * 128;
            int k = i2 >> 7, n = i2 & 127;
            Wt1[n * 128 + k] = f2bf(W1[k * 128 + n]);
        }
        return;
    }
    if (bid == 832) {
        __shared__ float lds[48 * 129 + 96];
        float* a   = lds + 48 * 129;
        float* bsh = a + 48;
        if (tid < 48) {
            float av = bn_scale[tid] * rsqrtf(bn_var[tid] + BN_EPS);
            a[tid] = av;
            bsh[tid] = bn_bias[tid] - bn_mean[tid] * av;
        }
        for (int idx = tid; idx < 48 * 128; idx += 256) {
            int k = idx >> 7, n = idx & 127;
            lds[k * 129 + n] = W0[k * 128 + n];
        }
        __syncthreads();
        #pragma unroll 4
        for (int it = 0; it < 32; ++it) {
            int n = (tid >> 6) + it * 4;
            int k = tid & 63;
            float v = (k < 48) ? lds[k * 129 + n] * a[k] : 0.f;
            Wt0[n * 64 + k] = f2bf(v);
        }
        if (tid < 128) {
            float s = b0[tid];
            #pragma unroll
            for (int k = 0; k < 48; ++k) s += bsh[k] * lds[k * 129 + tid];
            b0p[tid] = s;
        }
        return;
    }
    for (int e = tid; e < 32 * 48; e += 256) {
        int dd = e / 48, j = e - dd * 48;
        float v = (j < 47) ? b2[dd * 47 + j] : 0.f;
        if (j < 32) v *= LOG2E;
        b2p[e] = v;
    }
}

// r13 best (72us) + four subtractive cuts:
// (a) exp2-fold: W/H weights pre-scaled by log2e in prep -> raw v_exp_f32 in
//     both softmaxes (-32 muls/pass from in front of the exps).
// (b) ks=0 h2 fragments hoisted to registers (pass-invariant!): -4 ds_read_b128
//     per pass (25% of phase-4 h2 LDS reads). +16 VGPR; 124 <= 128 budget.
// (c) ld_local accumulates log2 (raw v_log_f32); one xln2 at the final write.
// (d) phase-1 merged: passthrough copy fused into the h0 staging loop
//     (x[32:64] loaded once, -512 global loads/block).
__launch_bounds__(256, 4)
__global__ void nsc_mfma(const float* __restrict__ x, const float* __restrict__ c,
                         const unsigned short* __restrict__ Wt0, const float* __restrict__ b0p,
                         const unsigned short* __restrict__ Wt1, const float* __restrict__ b1,
                         const unsigned short* __restrict__ Wt2, const float* __restrict__ b2p,
                         float* __restrict__ out, int N) {
    // region A [0,17408):       h0 [64][72] bf16  ->  h2 [64][136] bf16 (live through GEMM2)
    // region B [17408,38912):   h1 [64][136] bf16 ->  pw 4x[64][20] f32 (20480) + ldp [4][64] f32
    __shared__ __align__(16) char smem[38912];
    unsigned short* h0 = (unsigned short*)smem;            // stride 72
    unsigned short* h2 = (unsigned short*)smem;            // stride 136
    unsigned short* h1 = (unsigned short*)(smem + 17408);  // stride 136
    float*          ldp = (float*)(smem + 17408 + 20480);  // [4][64]

    const int tid  = threadIdx.x;
    const int lane = tid & 63;
    const int l    = lane & 15;
    const int q    = lane >> 4;
    const int wu   = __builtin_amdgcn_readfirstlane(tid >> 6);
    const int r0   = blockIdx.x * ROWS;
    float* pw = (float*)(smem + 17408) + wu * (64 * 20);   // per-wave staging, stride 20

    // ---- phase 1: raw inputs -> h0 bf16 (vectorized); xc passthrough fused ----
    {
        #pragma unroll
        for (int it = 0; it < 4; ++it) {
            int e = tid + it * 256;            // 0..1023
            int r = e >> 4, jb = (e & 15) << 2;
            int row = r0 + r;
            float4v v = {0.f, 0.f, 0.f, 0.f};
            if (jb < 32) {
                v = *(const float4v*)(x + (size_t)row * 64 + 32 + jb);
                *(float4v*)(out + (size_t)row * 64 + 32 + jb) = v;   // passthrough
            } else if (jb < 48) {
                v = *(const float4v*)(c + (size_t)row * 16 + (jb - 32));
            }
            short4v s;
            s[0] = (short)f2bf(v[0]); s[1] = (short)f2bf(v[1]);
            s[2] = (short)f2bf(v[2]); s[3] = (short)f2bf(v[3]);
            *(short4v*)(h0 + r * 72 + jb) = s;
        }
    }
    __syncthreads();

    // ---- phase 2: GEMM0  h1 = swish(h0 @ W0' + b0'), M=64 N=128 K=64(padded) ----
    {
        float4v acc[2][4];
        float4v z = {0.f, 0.f, 0.f, 0.f};
        #pragma unroll
        for (int nt = 0; nt < 2; ++nt)
            #pragma unroll
            for (int mt = 0; mt < 4; ++mt) acc[nt][mt] = z;
        #pragma unroll
        for (int ks = 0; ks < 2; ++ks) {
            short8 a[4];
            #pragma unroll
            for (int mt = 0; mt < 4; ++mt)
                a[mt] = *(const short8*)(h0 + (mt * 16 + l) * 72 + ks * 32 + (q << 3));
            #pragma unroll
            for (int nt = 0; nt < 2; ++nt) {
                int n0 = (wu * 2 + nt) * 16;
                short8 b = *(const short8*)(Wt0 + (n0 + l) * 64 + ks * 32 + (q << 3));
                #pragma unroll
                for (int mt = 0; mt < 4; ++mt)
                    acc[nt][mt] = __builtin_amdgcn_mfma_f32_16x16x32_bf16(a[mt], b, acc[nt][mt], 0, 0, 0);
            }
        }
        #pragma unroll
        for (int nt = 0; nt < 2; ++nt) {
            int n0 = (wu * 2 + nt) * 16;
            float bb = b0p[n0 + l];
            #pragma unroll
            for (int mt = 0; mt < 4; ++mt)
                #pragma unroll
                for (int r = 0; r < 4; ++r)
                    h1[(mt * 16 + q * 4 + r) * 136 + n0 + l] = f2bf(swish_f(acc[nt][mt][r] + bb));
        }
    }
    __syncthreads();

    // ---- phase 3: GEMM1  h2 = swish(h1 @ W1 + b1), M=64 N=128 K=128 ----
    {
        float4v acc[2][4];
        float4v z = {0.f, 0.f, 0.f, 0.f};
        #pragma unroll
        for (int nt = 0; nt < 2; ++nt)
            #pragma unroll
            for (int mt = 0; mt < 4; ++mt) acc[nt][mt] = z;
        #pragma unroll
        for (int ks = 0; ks < 4; ++ks) {
            short8 a[4];
            #pragma unroll
            for (int mt = 0; mt < 4; ++mt)
                a[mt] = *(const short8*)(h1 + (mt * 16 + l) * 136 + ks * 32 + (q << 3));
            #pragma unroll
            for (int nt = 0; nt < 2; ++nt) {
                int n0 = (wu * 2 + nt) * 16;
                short8 b = *(const short8*)(Wt1 + (n0 + l) * 128 + ks * 32 + (q << 3));
                #pragma unroll
                for (int mt = 0; mt < 4; ++mt)
                    acc[nt][mt] = __builtin_amdgcn_mfma_f32_16x16x32_bf16(a[mt], b, acc[nt][mt], 0, 0, 0);
            }
        }
        #pragma unroll
        for (int nt = 0; nt < 2; ++nt) {
            int n0 = (wu * 2 + nt) * 16;
            float bb = b1[n0 + l];
            #pragma unroll
            for (int mt = 0; mt < 4; ++mt)
                #pragma unroll
                for (int r = 0; r < 4; ++r)
                    h2[(mt * 16 + q * 4 + r) * 136 + n0 + l] = f2bf(swish_f(acc[nt][mt][r] + bb));
        }
    }
    __syncthreads();   // h1 dead -> pw reuses region B; h2 live in region A

    // ---- phase 4: GEMM2 (swapped: p^T tiles) + 3-stage spline, descent search ----
    float ld_local = 0.f;
    float yreg[8];
    // all 8 t's for this lane are consecutive floats of one x row: 2 dwordx4
    float tv[8];
    {
        const float* xr = x + (size_t)(r0 + lane) * 64 + wu * 8;
        *(float4v*)(tv)     = *(const float4v*)(xr);
        *(float4v*)(tv + 4) = *(const float4v*)(xr + 4);
    }
    // ks=0 h2 fragments are pass-invariant: hoist into registers (+16 VGPR)
    short8 bfc[4];
    #pragma unroll
    for (int smt = 0; smt < 4; ++smt)
        bfc[smt] = *(const short8*)(h2 + (smt * 16 + l) * 136 + (q << 3));
    for (int pass = 0; pass < 8; ++pass) {
        const int d = wu * 8 + pass;
        float t = tv[pass];
        float4v bj0 = *(const float4v*)(b2p + d * 48 +      (q << 2));
        float4v bj1 = *(const float4v*)(b2p + d * 48 + 16 + (q << 2));
        float4v bj2 = *(const float4v*)(b2p + d * 48 + 32 + (q << 2));
        bool inb = (t >= 0.f) && (t <= 1.f);
        float tc = fminf(fmaxf(t, 0.f), 1.f);

        // bias-init: acc[jt][smt][r] holds param jt*16+4q+r -> C-in = bj_jt
        float4v acc[3][4];
        #pragma unroll
        for (int smt = 0; smt < 4; ++smt) {
            acc[0][smt] = bj0; acc[1][smt] = bj1; acc[2][smt] = bj2;
        }
        __builtin_amdgcn_s_setprio(1);
        #pragma unroll
        for (int ks = 0; ks < 4; ++ks) {
            short8 bf[4];
            #pragma unroll
            for (int smt = 0; smt < 4; ++smt)
                bf[smt] = (ks == 0) ? bfc[smt]
                        : *(const short8*)(h2 + (smt * 16 + l) * 136 + ks * 32 + (q << 3));
            #pragma unroll
            for (int jt = 0; jt < 3; ++jt) {
                short8 a = *(const short8*)(Wt2 + (size_t)(d * 48 + jt * 16 + l) * 128 + ks * 32 + (q << 3));
                #pragma unroll
                for (int smt = 0; smt < 4; ++smt)
                    acc[jt][smt] = __builtin_amdgcn_mfma_f32_16x16x32_bf16(a, bf[smt], acc[jt][smt], 0, 0, 0);
            }
        }
        __builtin_amdgcn_s_setprio(0);

        float prW[16], prH[16];
        // ---- DS burst (per-wave in-order queue): W-write, W-read, H-write,
        //      H-read, D-write all in flight; W-compute overlaps H/D round-trips.
        #pragma unroll
        for (int smt = 0; smt < 4; ++smt)
            *(float4v*)(pw + (smt * 16 + l) * 20 + (q << 2)) = acc[0][smt];
        #pragma unroll
        for (int c2 = 0; c2 < 4; ++c2)
            *(float4v*)(prW + c2 * 4) = *(const float4v*)(pw + lane * 20 + c2 * 4);
        #pragma unroll
        for (int smt = 0; smt < 4; ++smt)
            *(float4v*)(pw + (smt * 16 + l) * 20 + (q << 2)) = acc[1][smt];
        #pragma unroll
        for (int c2 = 0; c2 < 4; ++c2)
            *(float4v*)(prH + c2 * 4) = *(const float4v*)(pw + lane * 20 + c2 * 4);
        #pragma unroll
        for (int smt = 0; smt < 4; ++smt)
            *(float4v*)(pw + (smt * 16 + l) * 20 + (q << 2)) = acc[2][smt];

        // ---- stage W: softmax via raw 2^x (weights pre-folded) + descent ----
        #pragma unroll
        for (int i = 0; i < 16; ++i) prW[i] = exp2_f(prW[i]);
        float pw0 = prW[0] + prW[1],   pw1 = prW[2] + prW[3];
        float pw2 = prW[4] + prW[5],   pw3 = prW[6] + prW[7];
        float pw4 = prW[8] + prW[9],   pw5 = prW[10] + prW[11];
        float pw6 = prW[12] + prW[13], pw7 = prW[14] + prW[15];
        float qw0 = pw0 + pw1, qw1 = pw2 + pw3, qw2 = pw4 + pw5, qw3 = pw6 + pw7;
        float ow0 = qw0 + qw1, ow1 = qw2 + qw3;
        float sW = ow0 + ow1;
        float ts = tc * sW;                       // search in unnormalized units
        bool b3 = (ts >= ow0);
        float base = b3 ? ow0 : 0.f;
        float qsel = b3 ? qw2 : qw0;
        bool b2 = (ts >= base + qsel);
        base += b2 ? qsel : 0.f;
        float psel = b2 ? (b3 ? pw6 : pw2) : (b3 ? pw4 : pw0);
        bool b1 = (ts >= base + psel);
        base += b1 ? psel : 0.f;
        float eev = b1 ? (b2 ? (b3 ? prW[14] : prW[6]) : (b3 ? prW[10] : prW[2]))
                       : (b2 ? (b3 ? prW[12] : prW[4]) : (b3 ? prW[8]  : prW[0]));
        bool b0 = (ts >= base + eev);
        base += b0 ? eev : 0.f;
        float eod = b1 ? (b2 ? (b3 ? prW[15] : prW[7]) : (b3 ? prW[11] : prW[3]))
                       : (b2 ? (b3 ? prW[13] : prW[5]) : (b3 ? prW[9]  : prW[1]));
        float xkb = base;
        float dxb = b0 ? eod : eev;
        int idx = (b3 ? 8 : 0) + (b2 ? 4 : 0) + (b1 ? 2 : 0) + (b0 ? 1 : 0);

        // ---- D scalar reads: issued as soon as idx is known; latency hides
        //      under stage-H compute below ----
        int i0 = (idx > 0)  ? idx - 1 : 0;
        int i1 = (idx < 15) ? idx     : 14;
        float pa0 = pw[lane * 20 + i0];
        float pa1 = pw[lane * 20 + i1];

        // ---- stage H: softmax via raw 2^x; ykb/dyb via descent bits ----
        #pragma unroll
        for (int i = 0; i < 16; ++i) prH[i] = exp2_f(prH[i]);
        float ph0 = prH[0] + prH[1],   ph1 = prH[2] + prH[3];
        float ph2 = prH[4] + prH[5],   ph3 = prH[6] + prH[7];
        float ph4 = prH[8] + prH[9],   ph5 = prH[10] + prH[11];
        float ph6 = prH[12] + prH[13], ph7 = prH[14] + prH[15];
        float qh0 = ph0 + ph1, qh1 = ph2 + ph3, qh2 = ph4 + ph5, qh3 = ph6 + ph7;
        float oh0 = qh0 + qh1, oh1 = qh2 + qh3;
        float sH = oh0 + oh1;
        float invH = rcp_f(sH);
        float qhsel = b3 ? qh2 : qh0;
        float phsel = b2 ? (b3 ? ph6 : ph2) : (b3 ? ph4 : ph0);
        float ehev = b1 ? (b2 ? (b3 ? prH[14] : prH[6]) : (b3 ? prH[10] : prH[2]))
                        : (b2 ? (b3 ? prH[12] : prH[4]) : (b3 ? prH[8]  : prH[0]));
        float ehod = b1 ? (b2 ? (b3 ? prH[15] : prH[7]) : (b3 ? prH[11] : prH[3]))
                        : (b2 ? (b3 ? prH[13] : prH[5]) : (b3 ? prH[9]  : prH[1]));
        float ykb = (b3 ? oh0 : 0.f) + (b2 ? qhsel : 0.f) +
                    (b1 ? phsel : 0.f) + (b0 ? ehev : 0.f);
        float dyb = b0 ? ehod : ehev;

        float d0 = (idx == 0)  ? 1.f : softplus_f(pa0);
        float d1 = (idx == 15) ? 1.f : softplus_f(pa1);

        float rdx = rcp_f(dxb);
        float xi  = (ts - xkb) * rdx;        // == (tc - xkb_n)/dxb_n
        float dyn = dyb * invH;
        float ykn = ykb * invH;
        float s   = dyn * sW * rdx;          // (dyb/sH)/(dxb/sW)
        float xim = 1.f - xi;
        float x1m = xi * xim;
        float den = s + (d0 + d1 - 2.f * s) * x1m;
        float rden = rcp_f(den);
        float y_in = ykn + dyn * (s * xi * xi + d0 * x1m) * rden;
        float dydx = s * s * (d1 * xi * xi + 2.f * s * x1m + d0 * xim * xim) * (rden * rden);

        yreg[pass] = inb ? y_in : t;
        ld_local += inb ? log2_f(dydx) : 0.f;   // log2-accumulate; xln2 at end
    }

    // ---- epilogue: y from registers; log_det reduction (x ln2 once) ----
    {
        float4v* o = (float4v*)(out + (size_t)(r0 + lane) * 64 + wu * 8);
        o[0] = *(const float4v*)(yreg);
        o[1] = *(const float4v*)(yreg + 4);
    }
    ldp[wu * 64 + lane] = ld_local;
    __syncthreads();
    if (tid < 64) {
        out[(size_t)N * 64 + r0 + tid] =
            (ldp[tid] + ldp[64 + tid] + ldp[128 + tid] + ldp[192 + tid]) * LN2;
    }
}

extern "C" void kernel_launch(void* const* d_in, const int* in_sizes, int n_in,
                              void* d_out, int out_size, void* d_ws, size_t ws_size,
                              hipStream_t stream) {
    const float* x        = (const float*)d_in[0];
    const float* c        = (const float*)d_in[1];
    const float* bn_scale = (const float*)d_in[2];
    const float* bn_bias  = (const float*)d_in[3];
    const float* bn_mean  = (const float*)d_in[4];
    const float* bn_var   = (const float*)d_in[5];
    const float* W0       = (const float*)d_in[6];
    const float* b0       = (const float*)d_in[7];
    const float* W1       = (const float*)d_in[8];
    const float* b1       = (const float*)d_in[9];
    const float* W2       = (const float*)d_in[10];
    const float* b2       = (const float*)d_in[11];
    float* out = (float*)d_out;

    unsigned short* Wt0 = (unsigned short*)d_ws;           // 128*64
    unsigned short* Wt1 = Wt0 + 128 * 64;                  // 128*128
    unsigned short* Wt2 = Wt1 + 128 * 128;                 // 1536*128
    float*          b2p = (float*)(Wt2 + 1536 * 128);      // 32*48
    float*          b0p = b2p + 32 * 48;                   // 128

    const int N = in_sizes[0] / 64;
    prep_weights<<<834, 256, 0, stream>>>(W0, W1, W2, b0, b2,
                                          bn_scale, bn_bias, bn_mean, bn_var,
                                          Wt0, Wt1, Wt2, b0p, b2p);
    nsc_mfma<<<N / ROWS, 256, 0, stream>>>(x, c, Wt0, b0p, Wt1, b1, Wt2, b2p, out, N);
}